// Round 16
// baseline (344.952 us; speedup 1.0000x reference)
//
#include <hip/hip_runtime.h>
#include <cstdint>

typedef _Float16 f16;
typedef __attribute__((ext_vector_type(8)))  f16   v8h;
typedef __attribute__((ext_vector_type(16))) float v16f;
typedef __attribute__((ext_vector_type(4)))  float v4f;
typedef unsigned short ushort_t;

#define N_TOK  65536
#define DIM    256
#define K_CB   4096
#define BN     128         // tokens per block (stage-0)
#define NCHUNK 128         // 8 kci x 16 d-chunks (wave slice = 64 codes)
#define MARGIN_S  3.0e-3f  // stage-0 flag margin (~10 sigma of 1-pass fp16 error)
#define MARGIN_S2 2.0e-4f  // stage-1 flag margin (~1000 sigma of 3-pass error)

#define MFMA(a,b,c) __builtin_amdgcn_mfma_f32_32x32x16_f16(a,b,c,0,0,0)

static __device__ __forceinline__ v4f ntload4(const void* p) {
    return __builtin_nontemporal_load((const v4f*)p);
}
static __device__ __forceinline__ void ntstore4(void* p, v4f v) {
    __builtin_nontemporal_store(v, (v4f*)p);
}

// ---------------------------------------------------------------- pack cb -> fp16 hi+lo panels, fused b2
// chunk g = kci*16 + ci (128 chunks, 16 KB each): [slice 8][khalf 2][code 64][8 d] f16
__global__ void pack_cb(const float* __restrict__ cb, ushort_t* __restrict__ cbh,
                        ushort_t* __restrict__ cbl, float* __restrict__ b2,
                        int* __restrict__ cnts) {
    __shared__ float red[256];
    int tid = threadIdx.x;
    if (blockIdx.x == 0 && tid < 2) cnts[tid] = 0;     // fused counter reset
    int gid = blockIdx.x * 256 + tid;                  // 0..131071
    int k = gid >> 5, grp = gid & 31;                  // grp = d/8
    int ci = grp >> 1, khalf = grp & 1;
    int kci = k >> 9, c = k & 511;
    int wav = c >> 6, cloc = c & 63;
    const float* src = cb + (size_t)k * DIM + grp * 8;
    float4 v0 = *(const float4*)(src);
    float4 v1 = *(const float4*)(src + 4);
    float f[8] = {v0.x, v0.y, v0.z, v0.w, v1.x, v1.y, v1.z, v1.w};
    v8h hv, lv;
    float ss = 0.f;
#pragma unroll
    for (int e = 0; e < 8; ++e) {
        f16 h = (f16)f[e];
        hv[e] = h;
        lv[e] = (f16)(f[e] - (float)h);
        ss = fmaf(f[e], f[e], ss);
    }
    size_t base = ((size_t)(kci * 16 + ci)) * 8192 + wav * 1024 + khalf * 512 + cloc * 8;
    *(v8h*)(cbh + base) = hv;
    *(v8h*)(cbl + base) = lv;
    red[tid] = ss;
    __syncthreads();
#pragma unroll
    for (int s = 16; s > 0; s >>= 1) {
        if ((tid & 31) < s) red[tid] += red[tid + s];
        __syncthreads();
    }
    if ((tid & 31) == 0) b2[gid >> 5] = red[tid];
}

// ---------------------------------------------------------------- stage-0: fp16 1-pass argmax(s)
// 1024 threads = 16 waves; wave tile = 64 codes x 64 tokens (8 code-slices x 2 token-halves).
// acc = 64 AGPR/wave -> target 4 waves/SIMD.
__global__ __launch_bounds__(1024, 4) void argmin_kernel(
    const float* __restrict__ x, const ushort_t* __restrict__ cbh,
    const float* __restrict__ b2, int* __restrict__ bestIdx,
    int* __restrict__ cnts, int* __restrict__ flagList)
{
    __shared__ __align__(16) f16   Xh[32 * 128 * 8];  // 64 KB: [dgrpIdx 32][token 128][8 d]
    __shared__ __align__(16) float B2s[K_CB];         // 16 KB

    const int tid   = threadIdx.x;
    const int wid   = tid >> 6;    // 0..15
    const int ws    = wid & 7;     // code-slice
    const int th    = wid >> 3;    // token-half
    const int lane  = tid & 63;
    const int l31   = lane & 31;
    const int lhalf = lane >> 5;
    const int n0    = blockIdx.x * BN;

    // ---- stage x tile (hi only, NON-TEMPORAL: x has zero reuse, keep cbh L2-resident)
    {
        const int token = tid >> 3, dseg = tid & 7;   // each thread: 32 d of one token
        const float* xr = x + (size_t)(n0 + token) * DIM + dseg * 32;
#pragma unroll
        for (int sgrp = 0; sgrp < 4; ++sgrp) {
            v4f a = ntload4(xr + 8 * sgrp);
            v4f b = ntload4(xr + 8 * sgrp + 4);
            float f[8] = {a.x, a.y, a.z, a.w, b.x, b.y, b.z, b.w};
            v8h hv;
#pragma unroll
            for (int e = 0; e < 8; ++e) hv[e] = (f16)f[e];
            *(v8h*)(Xh + (((dseg * 4 + sgrp) * 128) + token) * 8) = hv;
        }
        const int o = tid * 4;
        *(float4*)(B2s + o) = *(const float4*)(b2 + o);
    }
    __syncthreads();

    // per-lane A source: slice's 64 codes; chunk stride 8192 ushorts (16 KB)
    const ushort_t* ap = cbh + (size_t)ws * 1024 + (size_t)lhalf * 512 + (size_t)l31 * 8;

#define LOAD_A(A, g_) do { \
        const ushort_t* p_ = ap + (size_t)(g_) * 8192; \
        A##0 = *(const v8h*)(p_); A##1 = *(const v8h*)(p_ + 256); } while (0)
#define READ_B(B, g_) do { \
        int boff_ = ((((g_) & 15) * 2 + lhalf) * 128 + th * 64 + l31) * 8; \
        B##0 = *(const v8h*)(Xh + boff_); B##1 = *(const v8h*)(Xh + boff_ + 256); } while (0)
#define MFMA4(A, B) do { \
        acc[0][0] = MFMA(A##0, B##0, acc[0][0]); \
        acc[0][1] = MFMA(A##0, B##1, acc[0][1]); \
        acc[1][0] = MFMA(A##1, B##0, acc[1][0]); \
        acc[1][1] = MFMA(A##1, B##1, acc[1][1]); } while (0)

    v16f vzero;
#pragma unroll
    for (int r = 0; r < 16; ++r) vzero[r] = 0.0f;
    v16f acc[2][2];
#pragma unroll
    for (int a = 0; a < 2; ++a)
#pragma unroll
        for (int b = 0; b < 2; ++b) acc[a][b] = vzero;

    float b1d[2] = {-3.0e38f, -3.0e38f};
    float b2d[2] = {-3.0e38f, -3.0e38f};
    int   b1i[2] = {0x7fffffff, 0x7fffffff};

    v8h Aa0, Aa1, Ab0, Ab1;
    v8h Ba0, Ba1, Bb0, Bb1;

    LOAD_A(Aa, 0); READ_B(Ba, 0);
    LOAD_A(Ab, 1); READ_B(Bb, 1);

#pragma unroll 1
    for (int g = 0; g < NCHUNK; g += 2) {
        MFMA4(Aa, Ba);
        { int gp = (g + 2 < NCHUNK) ? g + 2 : 0; LOAD_A(Aa, gp); READ_B(Ba, gp); }
        MFMA4(Ab, Bb);
        { int gp = (g + 3 < NCHUNK) ? g + 3 : 0; LOAD_A(Ab, gp); READ_B(Bb, gp); }

        if ((g & 15) == 14) {       // ---- fold kci into running top-2 (ties -> flag path), reset acc
            const int kci = g >> 4;
            const int bbase = (kci << 9) + ws * 64 + 4 * lhalf;
#pragma unroll
            for (int m = 0; m < 2; ++m) {
                const float* bp = B2s + bbase + m * 32;
                float4 q0 = *(const float4*)(bp);
                float4 q1 = *(const float4*)(bp + 8);
                float4 q2 = *(const float4*)(bp + 16);
                float4 q3 = *(const float4*)(bp + 24);
                float bw[16] = {q0.x, q0.y, q0.z, q0.w, q1.x, q1.y, q1.z, q1.w,
                                q2.x, q2.y, q2.z, q2.w, q3.x, q3.y, q3.z, q3.w};
                const int kbase = bbase + m * 32;
#pragma unroll
                for (int j = 0; j < 2; ++j) {
#pragma unroll
                    for (int r = 0; r < 16; ++r) {
                        float sv = fmaf(-0.5f, bw[r], acc[m][j][r]);
                        int k = kbase + (r & 3) + 8 * (r >> 2);
                        bool better = sv > b1d[j];
                        b2d[j] = fmaxf(fminf(b1d[j], sv), b2d[j]);
                        b1d[j] = fmaxf(b1d[j], sv);
                        b1i[j] = better ? k : b1i[j];
                    }
                    acc[m][j] = vzero;
                }
            }
        }
    }

    // ---- merge lane halves (token column lives in lane and lane^32)
#pragma unroll
    for (int j = 0; j < 2; ++j) {
        float o1 = __shfl_xor(b1d[j], 32);
        float o2 = __shfl_xor(b2d[j], 32);
        int   oi = __shfl_xor(b1i[j], 32);
        bool ow = o1 > b1d[j];
        float nb2 = fmaxf(fminf(b1d[j], o1), fmaxf(b2d[j], o2));
        b1i[j] = ow ? oi : b1i[j];
        b1d[j] = fmaxf(b1d[j], o1);
        b2d[j] = nb2;
    }

    __syncthreads();
    float* f1 = (float*)Xh;          // [16 waves][64 tokens] (Xh dead now)
    float* f2 = f1 + 1024;
    int*   fi = (int*)(f2 + 1024);
    if (lane < 32) {
#pragma unroll
        for (int j = 0; j < 2; ++j) {
            int idx = wid * 64 + j * 32 + l31;
            f1[idx] = b1d[j]; f2[idx] = b2d[j]; fi[idx] = b1i[j];
        }
    }
    __syncthreads();
    if (tid < BN) {
        const int t63 = tid & 63, thh = tid >> 6;
        float s1 = -3.0e38f, s2 = -3.0e38f; int si = 0x7fffffff;
#pragma unroll
        for (int w = 0; w < 8; ++w) {
            int idx = (thh * 8 + w) * 64 + t63;
            float c1 = f1[idx], c2 = f2[idx];
            int  ci1 = fi[idx];
            bool ow = c1 > s1;
            float nb2 = fmaxf(fminf(s1, c1), fmaxf(s2, c2));
            si = ow ? ci1 : si; s1 = fmaxf(s1, c1); s2 = nb2;
        }
        int n = n0 + tid;
        bestIdx[n] = si;
        if (s1 - s2 < MARGIN_S) {            // near-tie under fp16 error -> stage-1
            int pos = atomicAdd(&cnts[0], 1);
            flagList[pos] = n;
        }
    }
}

// ---------------------------------------------------------------- stage-1: fp16 3-pass, codebook-QUARTER split
// block (group, qid): 32 tokens x 1024 codes (chunks qid*32..qid*32+31).
__global__ __launch_bounds__(512) void refine1_kernel(
    const float* __restrict__ x, const ushort_t* __restrict__ cbh,
    const ushort_t* __restrict__ cbl, const float* __restrict__ b2,
    const int* __restrict__ cnts, const int* __restrict__ flagList,
    float* __restrict__ ps1, float* __restrict__ ps2, int* __restrict__ pidx)
{
    __shared__ __align__(16) f16   Xh[32 * 32 * 8];   // 16 KB
    __shared__ __align__(16) f16   Xl[32 * 32 * 8];   // 16 KB
    __shared__ __align__(16) float B2q[1024];         // 4 KB (this quarter's b2)

    const int tid   = threadIdx.x;
    const int wid   = tid >> 6;
    const int lane  = tid & 63;
    const int l31   = lane & 31;
    const int lhalf = lane >> 5;
    const int grpI  = blockIdx.x >> 2;
    const int qid   = blockIdx.x & 3;
    const int cnt   = cnts[0];
    const int f0    = grpI * 32;
    if (f0 >= cnt) return;

    {
        const int token = tid >> 4, dseg = tid & 15;  // 16 d per thread
        const int f = f0 + token;
        const int n = (f < cnt) ? flagList[f] : 0;    // deterministic padding (token 0)
        const float* xr = x + (size_t)n * DIM + dseg * 16;
#pragma unroll
        for (int s = 0; s < 2; ++s) {
            v4f a = ntload4(xr + 8 * s);
            v4f b = ntload4(xr + 8 * s + 4);
            float f8[8] = {a.x, a.y, a.z, a.w, b.x, b.y, b.z, b.w};
            v8h hv, lv;
#pragma unroll
            for (int e = 0; e < 8; ++e) {
                f16 h = (f16)f8[e];
                hv[e] = h; lv[e] = (f16)(f8[e] - (float)h);
            }
            int grp = dseg * 2 + s;                   // 0..31
            *(v8h*)(Xh + (grp * 32 + token) * 8) = hv;
            *(v8h*)(Xl + (grp * 32 + token) * 8) = lv;
        }
        if (tid < 256) *(float4*)(B2q + tid * 4) = *(const float4*)(b2 + qid * 1024 + tid * 4);
    }
    __syncthreads();

    const size_t qoff = (size_t)qid * 32 * 8192;
    const size_t loff = (size_t)wid * 1024 + (size_t)lhalf * 512 + (size_t)l31 * 8;
    const ushort_t* aph = cbh + qoff + loff;
    const ushort_t* apl = cbl + qoff + loff;

#define LOAD_A6(H0_, H1_, L0_, L1_, g_) do { \
        const ushort_t* ph_ = aph + (size_t)(g_) * 8192; \
        const ushort_t* pl_ = apl + (size_t)(g_) * 8192; \
        H0_ = *(const v8h*)(ph_); H1_ = *(const v8h*)(ph_ + 256); \
        L0_ = *(const v8h*)(pl_); L1_ = *(const v8h*)(pl_ + 256); } while (0)
#define READ_B6(BH_, BL_, g_) do { \
        int boff_ = ((((g_) & 15) * 2 + lhalf) * 32 + l31) * 8; \
        BH_ = *(const v8h*)(Xh + boff_); BL_ = *(const v8h*)(Xl + boff_); } while (0)
#define MFMA6(H0_, H1_, L0_, L1_, BH_, BL_) do { \
        acc0 = MFMA(H0_, BH_, acc0); acc1 = MFMA(H1_, BH_, acc1); \
        acc0 = MFMA(H0_, BL_, acc0); acc1 = MFMA(H1_, BL_, acc1); \
        acc0 = MFMA(L0_, BH_, acc0); acc1 = MFMA(L1_, BH_, acc1); } while (0)

    v16f vzero;
#pragma unroll
    for (int r = 0; r < 16; ++r) vzero[r] = 0.0f;
    v16f acc0 = vzero, acc1 = vzero;
    float b1d = -3.0e38f, b2d = -3.0e38f; int b1i = 0x7fffffff;

    v8h Ha0, Ha1, La0, La1, Hb0, Hb1, Lb0, Lb1;
    v8h BHa, BLa, BHb, BLb;

    LOAD_A6(Ha0, Ha1, La0, La1, 0); READ_B6(BHa, BLa, 0);
    LOAD_A6(Hb0, Hb1, Lb0, Lb1, 1); READ_B6(BHb, BLb, 1);

#pragma unroll 1
    for (int gl = 0; gl < 32; gl += 2) {
        MFMA6(Ha0, Ha1, La0, La1, BHa, BLa);
        { int gp = (gl + 2 < 32) ? gl + 2 : 0; LOAD_A6(Ha0, Ha1, La0, La1, gp); READ_B6(BHa, BLa, gp); }
        MFMA6(Hb0, Hb1, Lb0, Lb1, BHb, BLb);
        { int gp = (gl + 3 < 32) ? gl + 3 : 0; LOAD_A6(Hb0, Hb1, Lb0, Lb1, gp); READ_B6(BHb, BLb, gp); }

        if ((gl & 15) == 14) {
            const int kci_l = gl >> 4;
            const int bb_l  = (kci_l << 9) + wid * 64 + 4 * lhalf;
#pragma unroll
            for (int m = 0; m < 2; ++m) {
                const float* bp = B2q + bb_l + m * 32;
                float4 q0 = *(const float4*)(bp);
                float4 q1 = *(const float4*)(bp + 8);
                float4 q2 = *(const float4*)(bp + 16);
                float4 q3 = *(const float4*)(bp + 24);
                float bw[16] = {q0.x, q0.y, q0.z, q0.w, q1.x, q1.y, q1.z, q1.w,
                                q2.x, q2.y, q2.z, q2.w, q3.x, q3.y, q3.z, q3.w};
                const int kbase = qid * 1024 + bb_l + m * 32;
                v16f a = (m == 0) ? acc0 : acc1;
#pragma unroll
                for (int r = 0; r < 16; ++r) {
                    float sv = fmaf(-0.5f, bw[r], a[r]);
                    int k = kbase + (r & 3) + 8 * (r >> 2);
                    bool better = sv > b1d;
                    b2d = fmaxf(fminf(b1d, sv), b2d);
                    b1d = fmaxf(b1d, sv);
                    b1i = better ? k : b1i;
                }
            }
            acc0 = vzero; acc1 = vzero;
        }
    }

    {   // merge lane halves
        float o1 = __shfl_xor(b1d, 32);
        float o2 = __shfl_xor(b2d, 32);
        int   oi = __shfl_xor(b1i, 32);
        bool ow = o1 > b1d;
        float nb2 = fmaxf(fminf(b1d, o1), fmaxf(b2d, o2));
        b1i = ow ? oi : b1i;
        b1d = fmaxf(b1d, o1);
        b2d = nb2;
    }
    __syncthreads();
    float* f1 = (float*)Xh;          // [8 waves][32 tokens]
    float* f2 = f1 + 256;
    int*   fi = (int*)(f2 + 256);
    if (lane < 32) {
        int idx = wid * 32 + l31;
        f1[idx] = b1d; f2[idx] = b2d; fi[idx] = b1i;
    }
    __syncthreads();
    if (tid < 32 && f0 + tid < cnt) {
        float s1 = -3.0e38f, s2 = -3.0e38f; int si = 0x7fffffff;
#pragma unroll
        for (int w = 0; w < 8; ++w) {
            float c1 = f1[w * 32 + tid], c2 = f2[w * 32 + tid];
            int  ci1 = fi[w * 32 + tid];
            bool ow = c1 > s1;
            float nb2 = fmaxf(fminf(s1, c1), fmaxf(s2, c2));
            si = ow ? ci1 : si; s1 = fmaxf(s1, c1); s2 = nb2;
        }
        const int f = f0 + tid;
        ps1 [qid * 65536 + f] = s1;
        ps2 [qid * 65536 + f] = s2;
        pidx[qid * 65536 + f] = si;
    }
}

// ---------------------------------------------------------------- merge quarters -> bestIdx + flagList2
__global__ void merge_kernel(int* __restrict__ cnts, const int* __restrict__ flagList,
                             const float* __restrict__ ps1, const float* __restrict__ ps2,
                             const int* __restrict__ pidx, int* __restrict__ bestIdx,
                             int* __restrict__ flagList2)
{
    const int cnt = cnts[0];
    for (int f = blockIdx.x * 256 + threadIdx.x; f < cnt; f += gridDim.x * 256) {
        float s1 = -3.0e38f, s2 = -3.0e38f; int si = 0x7fffffff;
#pragma unroll
        for (int q = 0; q < 4; ++q) {
            float c1 = ps1[q * 65536 + f], c2 = ps2[q * 65536 + f];
            int  ci1 = pidx[q * 65536 + f];
            bool ow = c1 > s1;
            float nb2 = fmaxf(fminf(s1, c1), fmaxf(s2, c2));
            si = ow ? ci1 : si; s1 = fmaxf(s1, c1); s2 = nb2;
        }
        const int n = flagList[f];
        bestIdx[n] = si;
        if (s1 - s2 < MARGIN_S2) {           // still near a boundary -> fp64 exact
            int pos = atomicAdd(&cnts[1], 1);
            flagList2[pos] = n;
        }
    }
}

// ---------------------------------------------------------------- stage-2: fp64 exact
__global__ __launch_bounds__(512) void refine2_kernel(
    const float* __restrict__ x, const float* __restrict__ cb,
    const int* __restrict__ cnts, const int* __restrict__ flagList2,
    int* __restrict__ bestIdx)
{
    __shared__ float  xr[DIM];
    __shared__ double rd[512];
    __shared__ int    ri[512];
    const int tid = threadIdx.x;
    const int cnt2 = cnts[1];
    for (int f = blockIdx.x; f < cnt2; f += gridDim.x) {
        const int n = flagList2[f];
        __syncthreads();
        if (tid < 64) {
            v4f v = ntload4(x + (size_t)n * DIM + tid * 4);
            xr[tid * 4 + 0] = v.x; xr[tid * 4 + 1] = v.y;
            xr[tid * 4 + 2] = v.z; xr[tid * 4 + 3] = v.w;
        }
        __syncthreads();
        double best = 1e300; int bi = 0x7fffffff;
#pragma unroll
        for (int grp = 0; grp < 2; ++grp) {
            const int k0 = grp * 2048 + tid;          // codes k0, k0+512, k0+1024, k0+1536
            const float4* cr0 = reinterpret_cast<const float4*>(cb + (size_t)k0 * DIM);
            const float4* cr1 = reinterpret_cast<const float4*>(cb + (size_t)(k0 + 512) * DIM);
            const float4* cr2 = reinterpret_cast<const float4*>(cb + (size_t)(k0 + 1024) * DIM);
            const float4* cr3 = reinterpret_cast<const float4*>(cb + (size_t)(k0 + 1536) * DIM);
            double s0a = 0, s0b = 0, s1a = 0, s1b = 0;
            double s2a = 0, s2b = 0, s3a = 0, s3b = 0;
#pragma unroll 4
            for (int q = 0; q < 64; ++q) {
                float4 c0 = cr0[q], c1 = cr1[q], c2 = cr2[q], c3 = cr3[q];
                double x0 = xr[4 * q + 0], x1 = xr[4 * q + 1];
                double x2 = xr[4 * q + 2], x3 = xr[4 * q + 3];
                s0a += (double)c0.x * ((double)c0.x - 2.0 * x0) + (double)c0.y * ((double)c0.y - 2.0 * x1);
                s0b += (double)c0.z * ((double)c0.z - 2.0 * x2) + (double)c0.w * ((double)c0.w - 2.0 * x3);
                s1a += (double)c1.x * ((double)c1.x - 2.0 * x0) + (double)c1.y * ((double)c1.y - 2.0 * x1);
                s1b += (double)c1.z * ((double)c1.z - 2.0 * x2) + (double)c1.w * ((double)c1.w - 2.0 * x3);
                s2a += (double)c2.x * ((double)c2.x - 2.0 * x0) + (double)c2.y * ((double)c2.y - 2.0 * x1);
                s2b += (double)c2.z * ((double)c2.z - 2.0 * x2) + (double)c2.w * ((double)c2.w - 2.0 * x3);
                s3a += (double)c3.x * ((double)c3.x - 2.0 * x0) + (double)c3.y * ((double)c3.y - 2.0 * x1);
                s3b += (double)c3.z * ((double)c3.z - 2.0 * x2) + (double)c3.w * ((double)c3.w - 2.0 * x3);
            }
            double d0 = s0a + s0b, d1 = s1a + s1b, d2 = s2a + s2b, d3 = s3a + s3b;
            if (d0 < best || (d0 == best && k0        < bi)) { best = d0; bi = k0; }
            if (d1 < best || (d1 == best && k0 + 512  < bi)) { best = d1; bi = k0 + 512; }
            if (d2 < best || (d2 == best && k0 + 1024 < bi)) { best = d2; bi = k0 + 1024; }
            if (d3 < best || (d3 == best && k0 + 1536 < bi)) { best = d3; bi = k0 + 1536; }
        }
        rd[tid] = best; ri[tid] = bi;
        __syncthreads();
        for (int s = 256; s > 0; s >>= 1) {
            if (tid < s) {
                double od = rd[tid + s]; int oi = ri[tid + s];
                if (od < rd[tid] || (od == rd[tid] && oi < ri[tid])) { rd[tid] = od; ri[tid] = oi; }
            }
            __syncthreads();
        }
        if (tid == 0) bestIdx[n] = ri[0];
        __syncthreads();
    }
}

// ---------------------------------------------------------------- gather out rows
__global__ void gather_kernel(const float* __restrict__ cb, const int* __restrict__ bestIdx,
                              float* __restrict__ out)
{
    int t = blockIdx.x * 256 + threadIdx.x;
    int n = t >> 6, f4 = t & 63;
    int k = bestIdx[n];
    v4f v = *reinterpret_cast<const v4f*>(cb + (size_t)k * DIM + f4 * 4);
    ntstore4(out + (size_t)t * 4, v);
}

extern "C" void kernel_launch(void* const* d_in, const int* in_sizes, int n_in,
                              void* d_out, int out_size, void* d_ws, size_t ws_size,
                              hipStream_t stream)
{
    const float* x  = (const float*)d_in[0];
    const float* cb = (const float*)d_in[1];
    float* out = (float*)d_out;

    char* ws = (char*)d_ws;
    ushort_t* cbh      = (ushort_t*)ws;                     // 2 MB
    ushort_t* cbl      = (ushort_t*)(ws + 2097152);         // 2 MB
    float*    b2       = (float*)(ws + 4194304);            // 16 KB
    int*      bestIdx  = (int*)(ws + 4210688);              // 256 KB
    int*      cnts     = (int*)(ws + 4472832);              // 16 B  [cnt1, cnt2]
    int*      flagList = (int*)(ws + 4472848);              // 256 KB
    int*      flagList2= (int*)(ws + 4734992);              // 256 KB
    float*    ps1      = (float*)(ws + 4997136);            // 1 MB  [4][65536]
    float*    ps2      = (float*)(ws + 6045712);            // 1 MB
    int*      pidx     = (int*)(ws + 7094288);              // 1 MB  (end ~7.8 MB)

    pack_cb       <<<dim3(512),  dim3(256), 0, stream>>>(cb, cbh, cbl, b2, cnts);
    argmin_kernel <<<dim3(N_TOK / BN), dim3(1024), 0, stream>>>(x, cbh, b2, bestIdx, cnts, flagList);
    refine1_kernel<<<dim3(8192), dim3(512), 0, stream>>>(x, cbh, cbl, b2, cnts, flagList, ps1, ps2, pidx);
    merge_kernel  <<<dim3(64),   dim3(256), 0, stream>>>(cnts, flagList, ps1, ps2, pidx, bestIdx, flagList2);
    refine2_kernel<<<dim3(1024), dim3(512), 0, stream>>>(x, cb, cnts, flagList2, bestIdx);
    gather_kernel <<<dim3(N_TOK * 64 / 256), dim3(256), 0, stream>>>(cb, bestIdx, out);
}

// Round 17
// 234.102 us; speedup vs baseline: 1.4735x; 1.4735x over previous
//
#include <hip/hip_runtime.h>
#include <cstdint>

typedef _Float16 f16;
typedef __attribute__((ext_vector_type(8)))  f16   v8h;
typedef __attribute__((ext_vector_type(16))) float v16f;
typedef __attribute__((ext_vector_type(4)))  float v4f;
typedef unsigned short ushort_t;

#define N_TOK  65536
#define DIM    256
#define K_CB   4096
#define BN     128         // tokens per block (stage-0)
#define NCHUNK 128         // 8 kci x 16 d-chunks (wave slice = 64 codes)
#define MARGIN_S  3.0e-3f  // flag margin (~7.5 sigma of 1-pass fp16 gap error)
#define MARGIN_S2 2.0e-4f  // stage-1 flag margin (~1000 sigma of 3-pass error)

#define MFMA(a,b,c) __builtin_amdgcn_mfma_f32_32x32x16_f16(a,b,c,0,0,0)

static __device__ __forceinline__ v4f ntload4(const void* p) {
    return __builtin_nontemporal_load((const v4f*)p);
}
static __device__ __forceinline__ void ntstore4(void* p, v4f v) {
    __builtin_nontemporal_store(v, (v4f*)p);
}

// merge sorted triples (values desc) with indices for top-2
static __device__ __forceinline__ void merge5(float& s1, int& i1, float& s2, int& i2, float& s3,
                                              float o1, int oi1, float o2, int oi2, float o3) {
    bool aw = s1 >= o1;
    float w1 = aw ? s1 : o1;  int wi1 = aw ? i1 : oi1;
    float w2 = aw ? s2 : o2;  int wi2 = aw ? i2 : oi2;
    float w3 = aw ? s3 : o3;
    float l1 = aw ? o1 : s1;  int li1 = aw ? oi1 : i1;
    float l2 = aw ? o2 : s2;
    bool c = l1 > w2;
    s1 = w1; i1 = wi1;
    s2 = c ? l1 : w2; i2 = c ? li1 : wi2;
    s3 = c ? fmaxf(w2, l2) : fmaxf(w3, l1);
}

// ---------------------------------------------------------------- pack cb -> fp16 hi+lo panels, fused b2
// chunk g = kci*16 + ci (128 chunks, 16 KB each): [wave 8][khalf 2][code 64][8 d] f16
__global__ void pack_cb(const float* __restrict__ cb, ushort_t* __restrict__ cbh,
                        ushort_t* __restrict__ cbl, float* __restrict__ b2,
                        int* __restrict__ cnts) {
    __shared__ float red[256];
    int tid = threadIdx.x;
    if (blockIdx.x == 0 && tid < 4) cnts[tid] = 0;     // fused counter reset
    int gid = blockIdx.x * 256 + tid;                  // 0..131071
    int k = gid >> 5, grp = gid & 31;                  // grp = d/8
    int ci = grp >> 1, khalf = grp & 1;
    int kci = k >> 9, c = k & 511;
    int wav = c >> 6, cloc = c & 63;
    const float* src = cb + (size_t)k * DIM + grp * 8;
    float4 v0 = *(const float4*)(src);
    float4 v1 = *(const float4*)(src + 4);
    float f[8] = {v0.x, v0.y, v0.z, v0.w, v1.x, v1.y, v1.z, v1.w};
    v8h hv, lv;
    float ss = 0.f;
#pragma unroll
    for (int e = 0; e < 8; ++e) {
        f16 h = (f16)f[e];
        hv[e] = h;
        lv[e] = (f16)(f[e] - (float)h);
        ss = fmaf(f[e], f[e], ss);
    }
    size_t base = ((size_t)(kci * 16 + ci)) * 8192 + wav * 1024 + khalf * 512 + cloc * 8;
    *(v8h*)(cbh + base) = hv;
    *(v8h*)(cbl + base) = lv;
    red[tid] = ss;
    __syncthreads();
#pragma unroll
    for (int s = 16; s > 0; s >>= 1) {
        if ((tid & 31) < s) red[tid] += red[tid + s];
        __syncthreads();
    }
    if ((tid & 31) == 0) b2[gid >> 5] = red[tid];
}

// ---------------------------------------------------------------- stage-0: fp16 1-pass argmax(s), top-3 track
__global__ __launch_bounds__(512, 2) void argmin_kernel(
    const float* __restrict__ x, const ushort_t* __restrict__ cbh,
    const float* __restrict__ b2, int* __restrict__ bestIdx,
    int* __restrict__ cnts, int* __restrict__ flagList, int* __restrict__ liteList)
{
    __shared__ __align__(16) f16   Xh[32 * 128 * 8];  // 64 KB: [dgrpIdx 32][token 128][8 d]
    __shared__ __align__(16) float B2s[K_CB];         // 16 KB

    const int tid   = threadIdx.x;
    const int wid   = tid >> 6;
    const int lane  = tid & 63;
    const int l31   = lane & 31;
    const int lhalf = lane >> 5;
    const int n0    = blockIdx.x * BN;

    // ---- stage x tile (hi only, NON-TEMPORAL: x has zero reuse, keep cbh L2-resident)
    {
        const int token = tid >> 2, dseg = tid & 3;   // each thread: 64 d of one token
        const float* xr = x + (size_t)(n0 + token) * DIM + dseg * 64;
#pragma unroll
        for (int sgrp = 0; sgrp < 8; ++sgrp) {
            v4f a = ntload4(xr + 8 * sgrp);
            v4f b = ntload4(xr + 8 * sgrp + 4);
            float f[8] = {a.x, a.y, a.z, a.w, b.x, b.y, b.z, b.w};
            v8h hv;
#pragma unroll
            for (int e = 0; e < 8; ++e) hv[e] = (f16)f[e];
            *(v8h*)(Xh + ((dseg * 8 + sgrp) * 128 + token) * 8) = hv;
        }
        const int o = tid * 8;
        *(float4*)(B2s + o)     = *(const float4*)(b2 + o);
        *(float4*)(B2s + o + 4) = *(const float4*)(b2 + o + 4);
    }
    __syncthreads();

    // per-lane A source: wave's 64-code slice; chunk stride 8192 ushorts (16 KB)
    const ushort_t* ap = cbh + (size_t)wid * 1024 + (size_t)lhalf * 512 + (size_t)l31 * 8;

#define LOAD_A(A, g_) do { \
        const ushort_t* p_ = ap + (size_t)(g_) * 8192; \
        A##0 = *(const v8h*)(p_); A##1 = *(const v8h*)(p_ + 256); } while (0)
#define READ_B(B, g_) do { \
        int boff_ = ((((g_) & 15) * 2 + lhalf) * 128 + l31) * 8; \
        B##0 = *(const v8h*)(Xh + boff_);       B##1 = *(const v8h*)(Xh + boff_ + 256); \
        B##2 = *(const v8h*)(Xh + boff_ + 512); B##3 = *(const v8h*)(Xh + boff_ + 768); } while (0)
#define MFMA8(A, B) do { \
        acc[0][0] = MFMA(A##0, B##0, acc[0][0]); \
        acc[0][1] = MFMA(A##0, B##1, acc[0][1]); \
        acc[0][2] = MFMA(A##0, B##2, acc[0][2]); \
        acc[0][3] = MFMA(A##0, B##3, acc[0][3]); \
        acc[1][0] = MFMA(A##1, B##0, acc[1][0]); \
        acc[1][1] = MFMA(A##1, B##1, acc[1][1]); \
        acc[1][2] = MFMA(A##1, B##2, acc[1][2]); \
        acc[1][3] = MFMA(A##1, B##3, acc[1][3]); } while (0)

    v16f vzero;
#pragma unroll
    for (int r = 0; r < 16; ++r) vzero[r] = 0.0f;
    v16f acc[2][4];
#pragma unroll
    for (int a = 0; a < 2; ++a)
#pragma unroll
        for (int b = 0; b < 4; ++b) acc[a][b] = vzero;

    float b1d[4], b2d[4], b3d[4];
    int   b1i[4], b2i[4];
#pragma unroll
    for (int j = 0; j < 4; ++j) {
        b1d[j] = -3.0e38f; b2d[j] = -3.0e38f; b3d[j] = -3.0e38f;
        b1i[j] = 0x7fffffff; b2i[j] = 0x7fffffff;
    }

    v8h Aa0, Aa1, Ab0, Ab1;
    v8h Ba0, Ba1, Ba2, Ba3, Bb0, Bb1, Bb2, Bb3;

    LOAD_A(Aa, 0); READ_B(Ba, 0);
    LOAD_A(Ab, 1); READ_B(Bb, 1);

#pragma unroll 1
    for (int g = 0; g < NCHUNK; g += 2) {
        MFMA8(Aa, Ba);
        { int gp = (g + 2 < NCHUNK) ? g + 2 : 0; LOAD_A(Aa, gp); READ_B(Ba, gp); }
        MFMA8(Ab, Bb);
        { int gp = (g + 3 < NCHUNK) ? g + 3 : 0; LOAD_A(Ab, gp); READ_B(Bb, gp); }

        if ((g & 15) == 14) {       // ---- fold kci into running top-3, reset acc
            const int kci = g >> 4;
            const int bbase = (kci << 9) + wid * 64 + 4 * lhalf;
#pragma unroll
            for (int m = 0; m < 2; ++m) {
                const float* bp = B2s + bbase + m * 32;
                float4 q0 = *(const float4*)(bp);
                float4 q1 = *(const float4*)(bp + 8);
                float4 q2 = *(const float4*)(bp + 16);
                float4 q3 = *(const float4*)(bp + 24);
                float bw[16] = {q0.x, q0.y, q0.z, q0.w, q1.x, q1.y, q1.z, q1.w,
                                q2.x, q2.y, q2.z, q2.w, q3.x, q3.y, q3.z, q3.w};
                const int kbase = bbase + m * 32;
#pragma unroll
                for (int j = 0; j < 4; ++j) {
#pragma unroll
                    for (int r = 0; r < 16; ++r) {
                        float sv = fmaf(-0.5f, bw[r], acc[m][j][r]);
                        int k = kbase + (r & 3) + 8 * (r >> 2);
                        bool c1 = sv > b1d[j];
                        bool c2 = sv > b2d[j];
                        float nb3 = c2 ? b2d[j] : fmaxf(b3d[j], sv);
                        int   n2i = c1 ? b1i[j] : (c2 ? k : b2i[j]);
                        float nb2 = c1 ? b1d[j] : fmaxf(b2d[j], sv);
                        int   n1i = c1 ? k : b1i[j];
                        b1d[j] = fmaxf(b1d[j], sv);
                        b3d[j] = nb3; b2d[j] = nb2; b2i[j] = n2i; b1i[j] = n1i;
                    }
                    acc[m][j] = vzero;
                }
            }
        }
    }

    // ---- merge lane halves (token column lives in lane and lane^32)
#pragma unroll
    for (int j = 0; j < 4; ++j) {
        float o1 = __shfl_xor(b1d[j], 32);
        float o2 = __shfl_xor(b2d[j], 32);
        float o3 = __shfl_xor(b3d[j], 32);
        int  oi1 = __shfl_xor(b1i[j], 32);
        int  oi2 = __shfl_xor(b2i[j], 32);
        merge5(b1d[j], b1i[j], b2d[j], b2i[j], b3d[j], o1, oi1, o2, oi2, o3);
    }

    __syncthreads();
    float* f1  = (float*)Xh;         // [8 waves][128 tokens] (Xh dead now; 20 KB)
    float* f2  = f1 + 1024;
    float* f3  = f2 + 1024;
    int*   fi1 = (int*)(f3 + 1024);
    int*   fi2 = fi1 + 1024;
    if (lane < 32) {
#pragma unroll
        for (int j = 0; j < 4; ++j) {
            int idx = wid * 128 + j * 32 + l31;
            f1[idx] = b1d[j]; f2[idx] = b2d[j]; f3[idx] = b3d[j];
            fi1[idx] = b1i[j]; fi2[idx] = b2i[j];
        }
    }
    __syncthreads();
    if (tid < BN) {
        float s1 = -3.0e38f, s2 = -3.0e38f, s3 = -3.0e38f;
        int i1 = 0x7fffffff, i2 = 0x7fffffff;
#pragma unroll
        for (int w = 0; w < 8; ++w) {
            int idx = w * 128 + tid;
            merge5(s1, i1, s2, i2, s3, f1[idx], fi1[idx], f2[idx], fi2[idx], f3[idx]);
        }
        int n = n0 + tid;
        bestIdx[n] = i1;
        if (s1 - s2 < MARGIN_S) {
            if (s1 - s3 < MARGIN_S) {        // 3+ candidates -> full re-scan path
                int pos = atomicAdd(&cnts[0], 1);
                flagList[pos] = n;
            } else {                          // exactly 2 candidates -> lite fp64 duel
                int pos = atomicAdd(&cnts[2], 1);
                liteList[pos] = (n << 12) | i2;
            }
        }
    }
}

// ---------------------------------------------------------------- refine-lite: fp64 duel between i1 and i2
__global__ __launch_bounds__(256) void refine_lite(
    const float* __restrict__ x, const float* __restrict__ cb,
    const int* __restrict__ cnts, const int* __restrict__ liteList,
    int* __restrict__ bestIdx)
{
    const int tid = threadIdx.x;
    const int w = tid >> 6, lane = tid & 63, l31 = lane & 31;
    const int cnt3 = cnts[2];
    for (int t = blockIdx.x * 4 + w; t < cnt3; t += gridDim.x * 4) {
        const int ent = liteList[t];
        const int n = ent >> 12, i2 = ent & 4095;
        const int i1 = bestIdx[n];
        const int code = (lane < 32) ? i1 : i2;
        const float* cr = cb + (size_t)code * DIM + l31 * 8;
        const float* xr = x + (size_t)n * DIM + l31 * 8;
        double s = 0.0;
#pragma unroll
        for (int d = 0; d < 8; ++d) {
            double c = cr[d];
            s += c * (c - 2.0 * (double)xr[d]);
        }
#pragma unroll
        for (int off = 1; off < 32; off <<= 1) s += __shfl_xor(s, off, 64);
        double so = __shfl_xor(s, 32, 64);
        if (lane == 0) {
            // s = dist(i1), so = dist(i2)
            bestIdx[n] = (so < s || (so == s && i2 < i1)) ? i2 : i1;
        }
    }
}

// ---------------------------------------------------------------- stage-1: fp16 3-pass, codebook-QUARTER split
__global__ __launch_bounds__(512) void refine1_kernel(
    const float* __restrict__ x, const ushort_t* __restrict__ cbh,
    const ushort_t* __restrict__ cbl, const float* __restrict__ b2,
    const int* __restrict__ cnts, const int* __restrict__ flagList,
    float* __restrict__ ps1, float* __restrict__ ps2, int* __restrict__ pidx)
{
    __shared__ __align__(16) f16   Xh[32 * 32 * 8];   // 16 KB
    __shared__ __align__(16) f16   Xl[32 * 32 * 8];   // 16 KB
    __shared__ __align__(16) float B2q[1024];         // 4 KB (this quarter's b2)

    const int tid   = threadIdx.x;
    const int wid   = tid >> 6;
    const int lane  = tid & 63;
    const int l31   = lane & 31;
    const int lhalf = lane >> 5;
    const int grpI  = blockIdx.x >> 2;
    const int qid   = blockIdx.x & 3;
    const int cnt   = cnts[0];
    const int f0    = grpI * 32;
    if (f0 >= cnt) return;

    {
        const int token = tid >> 4, dseg = tid & 15;  // 16 d per thread
        const int f = f0 + token;
        const int n = (f < cnt) ? flagList[f] : 0;    // deterministic padding (token 0)
        const float* xr = x + (size_t)n * DIM + dseg * 16;
#pragma unroll
        for (int s = 0; s < 2; ++s) {
            v4f a = ntload4(xr + 8 * s);
            v4f b = ntload4(xr + 8 * s + 4);
            float f8[8] = {a.x, a.y, a.z, a.w, b.x, b.y, b.z, b.w};
            v8h hv, lv;
#pragma unroll
            for (int e = 0; e < 8; ++e) {
                f16 h = (f16)f8[e];
                hv[e] = h; lv[e] = (f16)(f8[e] - (float)h);
            }
            int grp = dseg * 2 + s;                   // 0..31
            *(v8h*)(Xh + (grp * 32 + token) * 8) = hv;
            *(v8h*)(Xl + (grp * 32 + token) * 8) = lv;
        }
        if (tid < 256) *(float4*)(B2q + tid * 4) = *(const float4*)(b2 + qid * 1024 + tid * 4);
    }
    __syncthreads();

    const size_t qoff = (size_t)qid * 32 * 8192;
    const size_t loff = (size_t)wid * 1024 + (size_t)lhalf * 512 + (size_t)l31 * 8;
    const ushort_t* aph = cbh + qoff + loff;
    const ushort_t* apl = cbl + qoff + loff;

#define LOAD_A6(H0_, H1_, L0_, L1_, g_) do { \
        const ushort_t* ph_ = aph + (size_t)(g_) * 8192; \
        const ushort_t* pl_ = apl + (size_t)(g_) * 8192; \
        H0_ = *(const v8h*)(ph_); H1_ = *(const v8h*)(ph_ + 256); \
        L0_ = *(const v8h*)(pl_); L1_ = *(const v8h*)(pl_ + 256); } while (0)
#define READ_B6(BH_, BL_, g_) do { \
        int boff_ = ((((g_) & 15) * 2 + lhalf) * 32 + l31) * 8; \
        BH_ = *(const v8h*)(Xh + boff_); BL_ = *(const v8h*)(Xl + boff_); } while (0)
#define MFMA6(H0_, H1_, L0_, L1_, BH_, BL_) do { \
        acc0 = MFMA(H0_, BH_, acc0); acc1 = MFMA(H1_, BH_, acc1); \
        acc0 = MFMA(H0_, BL_, acc0); acc1 = MFMA(H1_, BL_, acc1); \
        acc0 = MFMA(L0_, BH_, acc0); acc1 = MFMA(L1_, BH_, acc1); } while (0)

    v16f vzero;
#pragma unroll
    for (int r = 0; r < 16; ++r) vzero[r] = 0.0f;
    v16f acc0 = vzero, acc1 = vzero;
    float b1d = -3.0e38f, b2d = -3.0e38f; int b1i = 0x7fffffff;

    v8h Ha0, Ha1, La0, La1, Hb0, Hb1, Lb0, Lb1;
    v8h BHa, BLa, BHb, BLb;

    LOAD_A6(Ha0, Ha1, La0, La1, 0); READ_B6(BHa, BLa, 0);
    LOAD_A6(Hb0, Hb1, Lb0, Lb1, 1); READ_B6(BHb, BLb, 1);

#pragma unroll 1
    for (int gl = 0; gl < 32; gl += 2) {
        MFMA6(Ha0, Ha1, La0, La1, BHa, BLa);
        { int gp = (gl + 2 < 32) ? gl + 2 : 0; LOAD_A6(Ha0, Ha1, La0, La1, gp); READ_B6(BHa, BLa, gp); }
        MFMA6(Hb0, Hb1, Lb0, Lb1, BHb, BLb);
        { int gp = (gl + 3 < 32) ? gl + 3 : 0; LOAD_A6(Hb0, Hb1, Lb0, Lb1, gp); READ_B6(BHb, BLb, gp); }

        if ((gl & 15) == 14) {
            const int kci_l = gl >> 4;
            const int bb_l  = (kci_l << 9) + wid * 64 + 4 * lhalf;
#pragma unroll
            for (int m = 0; m < 2; ++m) {
                const float* bp = B2q + bb_l + m * 32;
                float4 q0 = *(const float4*)(bp);
                float4 q1 = *(const float4*)(bp + 8);
                float4 q2 = *(const float4*)(bp + 16);
                float4 q3 = *(const float4*)(bp + 24);
                float bw[16] = {q0.x, q0.y, q0.z, q0.w, q1.x, q1.y, q1.z, q1.w,
                                q2.x, q2.y, q2.z, q2.w, q3.x, q3.y, q3.z, q3.w};
                const int kbase = qid * 1024 + bb_l + m * 32;
                v16f a = (m == 0) ? acc0 : acc1;
#pragma unroll
                for (int r = 0; r < 16; ++r) {
                    float sv = fmaf(-0.5f, bw[r], a[r]);
                    int k = kbase + (r & 3) + 8 * (r >> 2);
                    bool better = sv > b1d;
                    b2d = fmaxf(fminf(b1d, sv), b2d);
                    b1d = fmaxf(b1d, sv);
                    b1i = better ? k : b1i;
                }
            }
            acc0 = vzero; acc1 = vzero;
        }
    }

    {   // merge lane halves
        float o1 = __shfl_xor(b1d, 32);
        float o2 = __shfl_xor(b2d, 32);
        int   oi = __shfl_xor(b1i, 32);
        bool ow = o1 > b1d;
        float nb2 = fmaxf(fminf(b1d, o1), fmaxf(b2d, o2));
        b1i = ow ? oi : b1i;
        b1d = fmaxf(b1d, o1);
        b2d = nb2;
    }
    __syncthreads();
    float* f1 = (float*)Xh;          // [8 waves][32 tokens]
    float* f2 = f1 + 256;
    int*   fi = (int*)(f2 + 256);
    if (lane < 32) {
        int idx = wid * 32 + l31;
        f1[idx] = b1d; f2[idx] = b2d; fi[idx] = b1i;
    }
    __syncthreads();
    if (tid < 32 && f0 + tid < cnt) {
        float s1 = -3.0e38f, s2 = -3.0e38f; int si = 0x7fffffff;
#pragma unroll
        for (int w = 0; w < 8; ++w) {
            float c1 = f1[w * 32 + tid], c2 = f2[w * 32 + tid];
            int  ci1 = fi[w * 32 + tid];
            bool ow = c1 > s1;
            float nb2 = fmaxf(fminf(s1, c1), fmaxf(s2, c2));
            si = ow ? ci1 : si; s1 = fmaxf(s1, c1); s2 = nb2;
        }
        const int f = f0 + tid;
        ps1 [qid * 65536 + f] = s1;
        ps2 [qid * 65536 + f] = s2;
        pidx[qid * 65536 + f] = si;
    }
}

// ---------------------------------------------------------------- merge quarters -> bestIdx + flagList2
__global__ void merge_kernel(int* __restrict__ cnts, const int* __restrict__ flagList,
                             const float* __restrict__ ps1, const float* __restrict__ ps2,
                             const int* __restrict__ pidx, int* __restrict__ bestIdx,
                             int* __restrict__ flagList2)
{
    const int cnt = cnts[0];
    for (int f = blockIdx.x * 256 + threadIdx.x; f < cnt; f += gridDim.x * 256) {
        float s1 = -3.0e38f, s2 = -3.0e38f; int si = 0x7fffffff;
#pragma unroll
        for (int q = 0; q < 4; ++q) {
            float c1 = ps1[q * 65536 + f], c2 = ps2[q * 65536 + f];
            int  ci1 = pidx[q * 65536 + f];
            bool ow = c1 > s1;
            float nb2 = fmaxf(fminf(s1, c1), fmaxf(s2, c2));
            si = ow ? ci1 : si; s1 = fmaxf(s1, c1); s2 = nb2;
        }
        const int n = flagList[f];
        bestIdx[n] = si;
        if (s1 - s2 < MARGIN_S2) {           // still near a boundary -> fp64 exact
            int pos = atomicAdd(&cnts[1], 1);
            flagList2[pos] = n;
        }
    }
}

// ---------------------------------------------------------------- stage-2: fp64 exact full scan
__global__ __launch_bounds__(512) void refine2_kernel(
    const float* __restrict__ x, const float* __restrict__ cb,
    const int* __restrict__ cnts, const int* __restrict__ flagList2,
    int* __restrict__ bestIdx)
{
    __shared__ float  xr[DIM];
    __shared__ double rd[512];
    __shared__ int    ri[512];
    const int tid = threadIdx.x;
    const int cnt2 = cnts[1];
    for (int f = blockIdx.x; f < cnt2; f += gridDim.x) {
        const int n = flagList2[f];
        __syncthreads();
        if (tid < 64) {
            v4f v = ntload4(x + (size_t)n * DIM + tid * 4);
            xr[tid * 4 + 0] = v.x; xr[tid * 4 + 1] = v.y;
            xr[tid * 4 + 2] = v.z; xr[tid * 4 + 3] = v.w;
        }
        __syncthreads();
        double best = 1e300; int bi = 0x7fffffff;
#pragma unroll
        for (int grp = 0; grp < 2; ++grp) {
            const int k0 = grp * 2048 + tid;
            const float4* cr0 = reinterpret_cast<const float4*>(cb + (size_t)k0 * DIM);
            const float4* cr1 = reinterpret_cast<const float4*>(cb + (size_t)(k0 + 512) * DIM);
            const float4* cr2 = reinterpret_cast<const float4*>(cb + (size_t)(k0 + 1024) * DIM);
            const float4* cr3 = reinterpret_cast<const float4*>(cb + (size_t)(k0 + 1536) * DIM);
            double s0a = 0, s0b = 0, s1a = 0, s1b = 0;
            double s2a = 0, s2b = 0, s3a = 0, s3b = 0;
#pragma unroll 4
            for (int q = 0; q < 64; ++q) {
                float4 c0 = cr0[q], c1 = cr1[q], c2 = cr2[q], c3 = cr3[q];
                double x0 = xr[4 * q + 0], x1 = xr[4 * q + 1];
                double x2 = xr[4 * q + 2], x3 = xr[4 * q + 3];
                s0a += (double)c0.x * ((double)c0.x - 2.0 * x0) + (double)c0.y * ((double)c0.y - 2.0 * x1);
                s0b += (double)c0.z * ((double)c0.z - 2.0 * x2) + (double)c0.w * ((double)c0.w - 2.0 * x3);
                s1a += (double)c1.x * ((double)c1.x - 2.0 * x0) + (double)c1.y * ((double)c1.y - 2.0 * x1);
                s1b += (double)c1.z * ((double)c1.z - 2.0 * x2) + (double)c1.w * ((double)c1.w - 2.0 * x3);
                s2a += (double)c2.x * ((double)c2.x - 2.0 * x0) + (double)c2.y * ((double)c2.y - 2.0 * x1);
                s2b += (double)c2.z * ((double)c2.z - 2.0 * x2) + (double)c2.w * ((double)c2.w - 2.0 * x3);
                s3a += (double)c3.x * ((double)c3.x - 2.0 * x0) + (double)c3.y * ((double)c3.y - 2.0 * x1);
                s3b += (double)c3.z * ((double)c3.z - 2.0 * x2) + (double)c3.w * ((double)c3.w - 2.0 * x3);
            }
            double d0 = s0a + s0b, d1 = s1a + s1b, d2 = s2a + s2b, d3 = s3a + s3b;
            if (d0 < best || (d0 == best && k0        < bi)) { best = d0; bi = k0; }
            if (d1 < best || (d1 == best && k0 + 512  < bi)) { best = d1; bi = k0 + 512; }
            if (d2 < best || (d2 == best && k0 + 1024 < bi)) { best = d2; bi = k0 + 1024; }
            if (d3 < best || (d3 == best && k0 + 1536 < bi)) { best = d3; bi = k0 + 1536; }
        }
        rd[tid] = best; ri[tid] = bi;
        __syncthreads();
        for (int s = 256; s > 0; s >>= 1) {
            if (tid < s) {
                double od = rd[tid + s]; int oi = ri[tid + s];
                if (od < rd[tid] || (od == rd[tid] && oi < ri[tid])) { rd[tid] = od; ri[tid] = oi; }
            }
            __syncthreads();
        }
        if (tid == 0) bestIdx[n] = ri[0];
        __syncthreads();
    }
}

// ---------------------------------------------------------------- gather out rows
__global__ void gather_kernel(const float* __restrict__ cb, const int* __restrict__ bestIdx,
                              float* __restrict__ out)
{
    int t = blockIdx.x * 256 + threadIdx.x;
    int n = t >> 6, f4 = t & 63;
    int k = bestIdx[n];
    v4f v = *reinterpret_cast<const v4f*>(cb + (size_t)k * DIM + f4 * 4);
    ntstore4(out + (size_t)t * 4, v);
}

extern "C" void kernel_launch(void* const* d_in, const int* in_sizes, int n_in,
                              void* d_out, int out_size, void* d_ws, size_t ws_size,
                              hipStream_t stream)
{
    const float* x  = (const float*)d_in[0];
    const float* cb = (const float*)d_in[1];
    float* out = (float*)d_out;

    char* ws = (char*)d_ws;
    ushort_t* cbh      = (ushort_t*)ws;                     // 2 MB
    ushort_t* cbl      = (ushort_t*)(ws + 2097152);         // 2 MB
    float*    b2       = (float*)(ws + 4194304);            // 16 KB
    int*      bestIdx  = (int*)(ws + 4210688);              // 256 KB
    int*      cnts     = (int*)(ws + 4472832);              // 16 B  [cntFull, cnt2, cntLite, pad]
    int*      flagList = (int*)(ws + 4472848);              // 256 KB
    int*      flagList2= (int*)(ws + 4734992);              // 256 KB
    float*    ps1      = (float*)(ws + 4997136);            // 1 MB  [4][65536]
    float*    ps2      = (float*)(ws + 6045712);            // 1 MB
    int*      pidx     = (int*)(ws + 7094288);              // 1 MB  (end ~7.8 MB)
    int*      liteList = (int*)ps1;                         // reuse: consumed before refine1 writes ps1

    pack_cb       <<<dim3(512),  dim3(256), 0, stream>>>(cb, cbh, cbl, b2, cnts);
    argmin_kernel <<<dim3(N_TOK / BN), dim3(512), 0, stream>>>(x, cbh, b2, bestIdx, cnts, flagList, liteList);
    refine_lite   <<<dim3(512),  dim3(256), 0, stream>>>(x, cb, cnts, liteList, bestIdx);
    refine1_kernel<<<dim3(8192), dim3(512), 0, stream>>>(x, cbh, cbl, b2, cnts, flagList, ps1, ps2, pidx);
    merge_kernel  <<<dim3(64),   dim3(256), 0, stream>>>(cnts, flagList, ps1, ps2, pidx, bestIdx, flagList2);
    refine2_kernel<<<dim3(1024), dim3(512), 0, stream>>>(x, cb, cnts, flagList2, bestIdx);
    gather_kernel <<<dim3(N_TOK * 64 / 256), dim3(256), 0, stream>>>(cb, bestIdx, out);
}

// Round 18
// 221.840 us; speedup vs baseline: 1.5550x; 1.0553x over previous
//
#include <hip/hip_runtime.h>
#include <cstdint>

typedef _Float16 f16;
typedef __attribute__((ext_vector_type(8)))  f16   v8h;
typedef __attribute__((ext_vector_type(16))) float v16f;
typedef __attribute__((ext_vector_type(4)))  float v4f;
typedef unsigned short ushort_t;

#define N_TOK  65536
#define DIM    256
#define K_CB   4096
#define BN     128         // tokens per block (stage-0)
#define NCHUNK 128         // 8 kci x 16 d-chunks (wave slice = 64 codes)
#define MARGIN_S  3.0e-3f  // flag margin (~7.5 sigma of 1-pass fp16 gap error)
#define MARGIN_S2 2.0e-4f  // stage-1 flag margin (~1000 sigma of 3-pass error)

#define MFMA(a,b,c) __builtin_amdgcn_mfma_f32_32x32x16_f16(a,b,c,0,0,0)
#define MED3(a,b,c) __builtin_amdgcn_fmed3f(a,b,c)

static __device__ __forceinline__ v4f ntload4(const void* p) {
    return __builtin_nontemporal_load((const v4f*)p);
}
static __device__ __forceinline__ void ntstore4(void* p, v4f v) {
    __builtin_nontemporal_store(v, (v4f*)p);
}

// merge sorted triples (values desc) with indices for top-2
static __device__ __forceinline__ void merge5(float& s1, int& i1, float& s2, int& i2, float& s3,
                                              float o1, int oi1, float o2, int oi2, float o3) {
    bool aw = s1 >= o1;
    float w1 = aw ? s1 : o1;  int wi1 = aw ? i1 : oi1;
    float w2 = aw ? s2 : o2;  int wi2 = aw ? i2 : oi2;
    float w3 = aw ? s3 : o3;
    float l1 = aw ? o1 : s1;  int li1 = aw ? oi1 : i1;
    float l2 = aw ? o2 : s2;
    bool c = l1 > w2;
    s1 = w1; i1 = wi1;
    s2 = c ? l1 : w2; i2 = c ? li1 : wi2;
    s3 = c ? fmaxf(w2, l2) : fmaxf(w3, l1);
}

// ---------------------------------------------------------------- pack cb -> fp16 hi+lo panels, fused b2
// chunk g = kci*16 + ci (128 chunks, 16 KB each): [wave 8][khalf 2][code 64][8 d] f16
__global__ void pack_cb(const float* __restrict__ cb, ushort_t* __restrict__ cbh,
                        ushort_t* __restrict__ cbl, float* __restrict__ b2,
                        int* __restrict__ cnts) {
    __shared__ float red[256];
    int tid = threadIdx.x;
    if (blockIdx.x == 0 && tid < 4) cnts[tid] = 0;     // fused counter reset
    int gid = blockIdx.x * 256 + tid;                  // 0..131071
    int k = gid >> 5, grp = gid & 31;                  // grp = d/8
    int ci = grp >> 1, khalf = grp & 1;
    int kci = k >> 9, c = k & 511;
    int wav = c >> 6, cloc = c & 63;
    const float* src = cb + (size_t)k * DIM + grp * 8;
    float4 v0 = *(const float4*)(src);
    float4 v1 = *(const float4*)(src + 4);
    float f[8] = {v0.x, v0.y, v0.z, v0.w, v1.x, v1.y, v1.z, v1.w};
    v8h hv, lv;
    float ss = 0.f;
#pragma unroll
    for (int e = 0; e < 8; ++e) {
        f16 h = (f16)f[e];
        hv[e] = h;
        lv[e] = (f16)(f[e] - (float)h);
        ss = fmaf(f[e], f[e], ss);
    }
    size_t base = ((size_t)(kci * 16 + ci)) * 8192 + wav * 1024 + khalf * 512 + cloc * 8;
    *(v8h*)(cbh + base) = hv;
    *(v8h*)(cbl + base) = lv;
    red[tid] = ss;
    __syncthreads();
#pragma unroll
    for (int s = 16; s > 0; s >>= 1) {
        if ((tid & 31) < s) red[tid] += red[tid + s];
        __syncthreads();
    }
    if ((tid & 31) == 0) b2[gid >> 5] = red[tid];
}

// ---------------------------------------------------------------- stage-0: fp16 1-pass argmax(s), top-3 track
__global__ __launch_bounds__(512, 2) void argmin_kernel(
    const float* __restrict__ x, const ushort_t* __restrict__ cbh,
    const float* __restrict__ b2, int* __restrict__ bestIdx,
    int* __restrict__ cnts, int* __restrict__ flagList, int* __restrict__ liteList)
{
    __shared__ __align__(16) f16   Xh[32 * 128 * 8];  // 64 KB: [dgrpIdx 32][token 128][8 d]
    __shared__ __align__(16) float B2s[K_CB];         // 16 KB

    const int tid   = threadIdx.x;
    const int wid   = tid >> 6;
    const int lane  = tid & 63;
    const int l31   = lane & 31;
    const int lhalf = lane >> 5;
    const int n0    = blockIdx.x * BN;

    // ---- stage x tile (hi only, NON-TEMPORAL: x has zero reuse, keep cbh L2-resident)
    {
        const int token = tid >> 2, dseg = tid & 3;   // each thread: 64 d of one token
        const float* xr = x + (size_t)(n0 + token) * DIM + dseg * 64;
#pragma unroll
        for (int sgrp = 0; sgrp < 8; ++sgrp) {
            v4f a = ntload4(xr + 8 * sgrp);
            v4f b = ntload4(xr + 8 * sgrp + 4);
            float f[8] = {a.x, a.y, a.z, a.w, b.x, b.y, b.z, b.w};
            v8h hv;
#pragma unroll
            for (int e = 0; e < 8; ++e) hv[e] = (f16)f[e];
            *(v8h*)(Xh + ((dseg * 8 + sgrp) * 128 + token) * 8) = hv;
        }
        const int o = tid * 8;
        *(float4*)(B2s + o)     = *(const float4*)(b2 + o);
        *(float4*)(B2s + o + 4) = *(const float4*)(b2 + o + 4);
    }
    __syncthreads();

    // per-lane A source: wave's 64-code slice; chunk stride 8192 ushorts (16 KB)
    const ushort_t* ap = cbh + (size_t)wid * 1024 + (size_t)lhalf * 512 + (size_t)l31 * 8;

#define LOAD_A(A, g_) do { \
        const ushort_t* p_ = ap + (size_t)(g_) * 8192; \
        A##0 = *(const v8h*)(p_); A##1 = *(const v8h*)(p_ + 256); } while (0)
#define READ_B(B, g_) do { \
        int boff_ = ((((g_) & 15) * 2 + lhalf) * 128 + l31) * 8; \
        B##0 = *(const v8h*)(Xh + boff_);       B##1 = *(const v8h*)(Xh + boff_ + 256); \
        B##2 = *(const v8h*)(Xh + boff_ + 512); B##3 = *(const v8h*)(Xh + boff_ + 768); } while (0)
#define MFMA8(A, B) do { \
        acc[0][0] = MFMA(A##0, B##0, acc[0][0]); \
        acc[0][1] = MFMA(A##0, B##1, acc[0][1]); \
        acc[0][2] = MFMA(A##0, B##2, acc[0][2]); \
        acc[0][3] = MFMA(A##0, B##3, acc[0][3]); \
        acc[1][0] = MFMA(A##1, B##0, acc[1][0]); \
        acc[1][1] = MFMA(A##1, B##1, acc[1][1]); \
        acc[1][2] = MFMA(A##1, B##2, acc[1][2]); \
        acc[1][3] = MFMA(A##1, B##3, acc[1][3]); } while (0)

    v16f vzero;
#pragma unroll
    for (int r = 0; r < 16; ++r) vzero[r] = 0.0f;
    v16f acc[2][4];
#pragma unroll
    for (int a = 0; a < 2; ++a)
#pragma unroll
        for (int b = 0; b < 4; ++b) acc[a][b] = vzero;

    float b1d[4], b2d[4], b3d[4];
    int   b1i[4], b2i[4];
#pragma unroll
    for (int j = 0; j < 4; ++j) {
        b1d[j] = -3.0e38f; b2d[j] = -3.0e38f; b3d[j] = -3.0e38f;
        b1i[j] = 0x7fffffff; b2i[j] = 0x7fffffff;
    }

    v8h Aa0, Aa1, Ab0, Ab1;
    v8h Ba0, Ba1, Ba2, Ba3, Bb0, Bb1, Bb2, Bb3;

    LOAD_A(Aa, 0); READ_B(Ba, 0);
    LOAD_A(Ab, 1); READ_B(Bb, 1);

#pragma unroll 1
    for (int g = 0; g < NCHUNK; g += 2) {
        MFMA8(Aa, Ba);
        { int gp = (g + 2 < NCHUNK) ? g + 2 : 0; LOAD_A(Aa, gp); READ_B(Ba, gp); }
        MFMA8(Ab, Bb);
        { int gp = (g + 3 < NCHUNK) ? g + 3 : 0; LOAD_A(Ab, gp); READ_B(Bb, gp); }

        if ((g & 15) == 14) {       // ---- fold kci into running top-3 (med3 form), reset acc
            const int kci = g >> 4;
            const int bbase = (kci << 9) + wid * 64 + 4 * lhalf;
#pragma unroll
            for (int m = 0; m < 2; ++m) {
                const float* bp = B2s + bbase + m * 32;
                float4 q0 = *(const float4*)(bp);
                float4 q1 = *(const float4*)(bp + 8);
                float4 q2 = *(const float4*)(bp + 16);
                float4 q3 = *(const float4*)(bp + 24);
                float bw[16] = {q0.x, q0.y, q0.z, q0.w, q1.x, q1.y, q1.z, q1.w,
                                q2.x, q2.y, q2.z, q2.w, q3.x, q3.y, q3.z, q3.w};
                const int kbase = bbase + m * 32;
#pragma unroll
                for (int j = 0; j < 4; ++j) {
#pragma unroll
                    for (int r = 0; r < 16; ++r) {
                        float sv = fmaf(-0.5f, bw[r], acc[m][j][r]);
                        int k = kbase + (r & 3) + 8 * (r >> 2);
                        bool c1 = sv > b1d[j];
                        bool c2 = sv > b2d[j];
                        b3d[j] = MED3(sv, b2d[j], b3d[j]);      // uses OLD b2d
                        int t2 = c2 ? k : b2i[j];
                        b2i[j] = c1 ? b1i[j] : t2;              // uses OLD b1i
                        b2d[j] = MED3(sv, b1d[j], b2d[j]);      // uses OLD b1d
                        b1i[j] = c1 ? k : b1i[j];
                        b1d[j] = fmaxf(b1d[j], sv);
                    }
                    acc[m][j] = vzero;
                }
            }
        }
    }

    // ---- merge lane halves (token column lives in lane and lane^32)
#pragma unroll
    for (int j = 0; j < 4; ++j) {
        float o1 = __shfl_xor(b1d[j], 32);
        float o2 = __shfl_xor(b2d[j], 32);
        float o3 = __shfl_xor(b3d[j], 32);
        int  oi1 = __shfl_xor(b1i[j], 32);
        int  oi2 = __shfl_xor(b2i[j], 32);
        merge5(b1d[j], b1i[j], b2d[j], b2i[j], b3d[j], o1, oi1, o2, oi2, o3);
    }

    __syncthreads();
    float* f1  = (float*)Xh;         // [8 waves][128 tokens] (Xh dead now; 20 KB)
    float* f2  = f1 + 1024;
    float* f3  = f2 + 1024;
    int*   fi1 = (int*)(f3 + 1024);
    int*   fi2 = fi1 + 1024;
    if (lane < 32) {
#pragma unroll
        for (int j = 0; j < 4; ++j) {
            int idx = wid * 128 + j * 32 + l31;
            f1[idx] = b1d[j]; f2[idx] = b2d[j]; f3[idx] = b3d[j];
            fi1[idx] = b1i[j]; fi2[idx] = b2i[j];
        }
    }
    __syncthreads();
    if (tid < BN) {
        float s1 = -3.0e38f, s2 = -3.0e38f, s3 = -3.0e38f;
        int i1 = 0x7fffffff, i2 = 0x7fffffff;
#pragma unroll
        for (int w = 0; w < 8; ++w) {
            int idx = w * 128 + tid;
            merge5(s1, i1, s2, i2, s3, f1[idx], fi1[idx], f2[idx], fi2[idx], f3[idx]);
        }
        int n = n0 + tid;
        bestIdx[n] = i1;
        if (s1 - s2 < MARGIN_S) {
            if (s1 - s3 < MARGIN_S) {        // 3+ candidates -> full re-scan path
                int pos = atomicAdd(&cnts[0], 1);
                flagList[pos] = n;
            } else {                          // exactly 2 candidates -> lite fp64 duel
                int pos = atomicAdd(&cnts[2], 1);
                liteList[pos] = (n << 12) | i2;
            }
        }
    }
}

// ---------------------------------------------------------------- refine-lite: fp64 duel between i1 and i2
__global__ __launch_bounds__(256) void refine_lite(
    const float* __restrict__ x, const float* __restrict__ cb,
    const int* __restrict__ cnts, const int* __restrict__ liteList,
    int* __restrict__ bestIdx)
{
    const int tid = threadIdx.x;
    const int w = tid >> 6, lane = tid & 63, l31 = lane & 31;
    const int cnt3 = cnts[2];
    for (int t = blockIdx.x * 4 + w; t < cnt3; t += gridDim.x * 4) {
        const int ent = liteList[t];
        const int n = ent >> 12, i2 = ent & 4095;
        const int i1 = bestIdx[n];
        const int code = (lane < 32) ? i1 : i2;
        const float* cr = cb + (size_t)code * DIM + l31 * 8;
        const float* xr = x + (size_t)n * DIM + l31 * 8;
        double s = 0.0;
#pragma unroll
        for (int d = 0; d < 8; ++d) {
            double c = cr[d];
            s += c * (c - 2.0 * (double)xr[d]);
        }
#pragma unroll
        for (int off = 1; off < 32; off <<= 1) s += __shfl_xor(s, off, 64);
        double so = __shfl_xor(s, 32, 64);
        if (lane == 0) {
            // s = dist(i1), so = dist(i2)
            bestIdx[n] = (so < s || (so == s && i2 < i1)) ? i2 : i1;
        }
    }
}

// ---------------------------------------------------------------- stage-1: fp16 3-pass, codebook-QUARTER split
__global__ __launch_bounds__(512) void refine1_kernel(
    const float* __restrict__ x, const ushort_t* __restrict__ cbh,
    const ushort_t* __restrict__ cbl, const float* __restrict__ b2,
    const int* __restrict__ cnts, const int* __restrict__ flagList,
    float* __restrict__ ps1, float* __restrict__ ps2, int* __restrict__ pidx)
{
    __shared__ __align__(16) f16   Xh[32 * 32 * 8];   // 16 KB
    __shared__ __align__(16) f16   Xl[32 * 32 * 8];   // 16 KB
    __shared__ __align__(16) float B2q[1024];         // 4 KB (this quarter's b2)

    const int tid   = threadIdx.x;
    const int wid   = tid >> 6;
    const int lane  = tid & 63;
    const int l31   = lane & 31;
    const int lhalf = lane >> 5;
    const int grpI  = blockIdx.x >> 2;
    const int qid   = blockIdx.x & 3;
    const int cnt   = cnts[0];
    const int f0    = grpI * 32;
    if (f0 >= cnt) return;

    {
        const int token = tid >> 4, dseg = tid & 15;  // 16 d per thread
        const int f = f0 + token;
        const int n = (f < cnt) ? flagList[f] : 0;    // deterministic padding (token 0)
        const float* xr = x + (size_t)n * DIM + dseg * 16;
#pragma unroll
        for (int s = 0; s < 2; ++s) {
            v4f a = ntload4(xr + 8 * s);
            v4f b = ntload4(xr + 8 * s + 4);
            float f8[8] = {a.x, a.y, a.z, a.w, b.x, b.y, b.z, b.w};
            v8h hv, lv;
#pragma unroll
            for (int e = 0; e < 8; ++e) {
                f16 h = (f16)f8[e];
                hv[e] = h; lv[e] = (f16)(f8[e] - (float)h);
            }
            int grp = dseg * 2 + s;                   // 0..31
            *(v8h*)(Xh + (grp * 32 + token) * 8) = hv;
            *(v8h*)(Xl + (grp * 32 + token) * 8) = lv;
        }
        if (tid < 256) *(float4*)(B2q + tid * 4) = *(const float4*)(b2 + qid * 1024 + tid * 4);
    }
    __syncthreads();

    const size_t qoff = (size_t)qid * 32 * 8192;
    const size_t loff = (size_t)wid * 1024 + (size_t)lhalf * 512 + (size_t)l31 * 8;
    const ushort_t* aph = cbh + qoff + loff;
    const ushort_t* apl = cbl + qoff + loff;

#define LOAD_A6(H0_, H1_, L0_, L1_, g_) do { \
        const ushort_t* ph_ = aph + (size_t)(g_) * 8192; \
        const ushort_t* pl_ = apl + (size_t)(g_) * 8192; \
        H0_ = *(const v8h*)(ph_); H1_ = *(const v8h*)(ph_ + 256); \
        L0_ = *(const v8h*)(pl_); L1_ = *(const v8h*)(pl_ + 256); } while (0)
#define READ_B6(BH_, BL_, g_) do { \
        int boff_ = ((((g_) & 15) * 2 + lhalf) * 32 + l31) * 8; \
        BH_ = *(const v8h*)(Xh + boff_); BL_ = *(const v8h*)(Xl + boff_); } while (0)
#define MFMA6(H0_, H1_, L0_, L1_, BH_, BL_) do { \
        acc0 = MFMA(H0_, BH_, acc0); acc1 = MFMA(H1_, BH_, acc1); \
        acc0 = MFMA(H0_, BL_, acc0); acc1 = MFMA(H1_, BL_, acc1); \
        acc0 = MFMA(L0_, BH_, acc0); acc1 = MFMA(L1_, BH_, acc1); } while (0)

    v16f vzero;
#pragma unroll
    for (int r = 0; r < 16; ++r) vzero[r] = 0.0f;
    v16f acc0 = vzero, acc1 = vzero;
    float b1d = -3.0e38f, b2d = -3.0e38f; int b1i = 0x7fffffff;

    v8h Ha0, Ha1, La0, La1, Hb0, Hb1, Lb0, Lb1;
    v8h BHa, BLa, BHb, BLb;

    LOAD_A6(Ha0, Ha1, La0, La1, 0); READ_B6(BHa, BLa, 0);
    LOAD_A6(Hb0, Hb1, Lb0, Lb1, 1); READ_B6(BHb, BLb, 1);

#pragma unroll 1
    for (int gl = 0; gl < 32; gl += 2) {
        MFMA6(Ha0, Ha1, La0, La1, BHa, BLa);
        { int gp = (gl + 2 < 32) ? gl + 2 : 0; LOAD_A6(Ha0, Ha1, La0, La1, gp); READ_B6(BHa, BLa, gp); }
        MFMA6(Hb0, Hb1, Lb0, Lb1, BHb, BLb);
        { int gp = (gl + 3 < 32) ? gl + 3 : 0; LOAD_A6(Hb0, Hb1, Lb0, Lb1, gp); READ_B6(BHb, BLb, gp); }

        if ((gl & 15) == 14) {
            const int kci_l = gl >> 4;
            const int bb_l  = (kci_l << 9) + wid * 64 + 4 * lhalf;
#pragma unroll
            for (int m = 0; m < 2; ++m) {
                const float* bp = B2q + bb_l + m * 32;
                float4 q0 = *(const float4*)(bp);
                float4 q1 = *(const float4*)(bp + 8);
                float4 q2 = *(const float4*)(bp + 16);
                float4 q3 = *(const float4*)(bp + 24);
                float bw[16] = {q0.x, q0.y, q0.z, q0.w, q1.x, q1.y, q1.z, q1.w,
                                q2.x, q2.y, q2.z, q2.w, q3.x, q3.y, q3.z, q3.w};
                const int kbase = qid * 1024 + bb_l + m * 32;
                v16f a = (m == 0) ? acc0 : acc1;
#pragma unroll
                for (int r = 0; r < 16; ++r) {
                    float sv = fmaf(-0.5f, bw[r], a[r]);
                    int k = kbase + (r & 3) + 8 * (r >> 2);
                    bool better = sv > b1d;
                    b2d = MED3(sv, b1d, b2d);
                    b1d = fmaxf(b1d, sv);
                    b1i = better ? k : b1i;
                }
            }
            acc0 = vzero; acc1 = vzero;
        }
    }

    {   // merge lane halves
        float o1 = __shfl_xor(b1d, 32);
        float o2 = __shfl_xor(b2d, 32);
        int   oi = __shfl_xor(b1i, 32);
        bool ow = o1 > b1d;
        float nb2 = fmaxf(fminf(b1d, o1), fmaxf(b2d, o2));
        b1i = ow ? oi : b1i;
        b1d = fmaxf(b1d, o1);
        b2d = nb2;
    }
    __syncthreads();
    float* f1 = (float*)Xh;          // [8 waves][32 tokens]
    float* f2 = f1 + 256;
    int*   fi = (int*)(f2 + 256);
    if (lane < 32) {
        int idx = wid * 32 + l31;
        f1[idx] = b1d; f2[idx] = b2d; fi[idx] = b1i;
    }
    __syncthreads();
    if (tid < 32 && f0 + tid < cnt) {
        float s1 = -3.0e38f, s2 = -3.0e38f; int si = 0x7fffffff;
#pragma unroll
        for (int w = 0; w < 8; ++w) {
            float c1 = f1[w * 32 + tid], c2 = f2[w * 32 + tid];
            int  ci1 = fi[w * 32 + tid];
            bool ow = c1 > s1;
            float nb2 = fmaxf(fminf(s1, c1), fmaxf(s2, c2));
            si = ow ? ci1 : si; s1 = fmaxf(s1, c1); s2 = nb2;
        }
        const int f = f0 + tid;
        ps1 [qid * 65536 + f] = s1;
        ps2 [qid * 65536 + f] = s2;
        pidx[qid * 65536 + f] = si;
    }
}

// ---------------------------------------------------------------- merge quarters -> bestIdx + flagList2
__global__ void merge_kernel(int* __restrict__ cnts, const int* __restrict__ flagList,
                             const float* __restrict__ ps1, const float* __restrict__ ps2,
                             const int* __restrict__ pidx, int* __restrict__ bestIdx,
                             int* __restrict__ flagList2)
{
    const int cnt = cnts[0];
    for (int f = blockIdx.x * 256 + threadIdx.x; f < cnt; f += gridDim.x * 256) {
        float s1 = -3.0e38f, s2 = -3.0e38f; int si = 0x7fffffff;
#pragma unroll
        for (int q = 0; q < 4; ++q) {
            float c1 = ps1[q * 65536 + f], c2 = ps2[q * 65536 + f];
            int  ci1 = pidx[q * 65536 + f];
            bool ow = c1 > s1;
            float nb2 = fmaxf(fminf(s1, c1), fmaxf(s2, c2));
            si = ow ? ci1 : si; s1 = fmaxf(s1, c1); s2 = nb2;
        }
        const int n = flagList[f];
        bestIdx[n] = si;
        if (s1 - s2 < MARGIN_S2) {           // still near a boundary -> fp64 exact
            int pos = atomicAdd(&cnts[1], 1);
            flagList2[pos] = n;
        }
    }
}

// ---------------------------------------------------------------- stage-2: fp64 exact full scan
__global__ __launch_bounds__(512) void refine2_kernel(
    const float* __restrict__ x, const float* __restrict__ cb,
    const int* __restrict__ cnts, const int* __restrict__ flagList2,
    int* __restrict__ bestIdx)
{
    __shared__ float  xr[DIM];
    __shared__ double rd[512];
    __shared__ int    ri[512];
    const int tid = threadIdx.x;
    const int cnt2 = cnts[1];
    for (int f = blockIdx.x; f < cnt2; f += gridDim.x) {
        const int n = flagList2[f];
        __syncthreads();
        if (tid < 64) {
            v4f v = ntload4(x + (size_t)n * DIM + tid * 4);
            xr[tid * 4 + 0] = v.x; xr[tid * 4 + 1] = v.y;
            xr[tid * 4 + 2] = v.z; xr[tid * 4 + 3] = v.w;
        }
        __syncthreads();
        double best = 1e300; int bi = 0x7fffffff;
#pragma unroll
        for (int grp = 0; grp < 2; ++grp) {
            const int k0 = grp * 2048 + tid;
            const float4* cr0 = reinterpret_cast<const float4*>(cb + (size_t)k0 * DIM);
            const float4* cr1 = reinterpret_cast<const float4*>(cb + (size_t)(k0 + 512) * DIM);
            const float4* cr2 = reinterpret_cast<const float4*>(cb + (size_t)(k0 + 1024) * DIM);
            const float4* cr3 = reinterpret_cast<const float4*>(cb + (size_t)(k0 + 1536) * DIM);
            double s0a = 0, s0b = 0, s1a = 0, s1b = 0;
            double s2a = 0, s2b = 0, s3a = 0, s3b = 0;
#pragma unroll 4
            for (int q = 0; q < 64; ++q) {
                float4 c0 = cr0[q], c1 = cr1[q], c2 = cr2[q], c3 = cr3[q];
                double x0 = xr[4 * q + 0], x1 = xr[4 * q + 1];
                double x2 = xr[4 * q + 2], x3 = xr[4 * q + 3];
                s0a += (double)c0.x * ((double)c0.x - 2.0 * x0) + (double)c0.y * ((double)c0.y - 2.0 * x1);
                s0b += (double)c0.z * ((double)c0.z - 2.0 * x2) + (double)c0.w * ((double)c0.w - 2.0 * x3);
                s1a += (double)c1.x * ((double)c1.x - 2.0 * x0) + (double)c1.y * ((double)c1.y - 2.0 * x1);
                s1b += (double)c1.z * ((double)c1.z - 2.0 * x2) + (double)c1.w * ((double)c1.w - 2.0 * x3);
                s2a += (double)c2.x * ((double)c2.x - 2.0 * x0) + (double)c2.y * ((double)c2.y - 2.0 * x1);
                s2b += (double)c2.z * ((double)c2.z - 2.0 * x2) + (double)c2.w * ((double)c2.w - 2.0 * x3);
                s3a += (double)c3.x * ((double)c3.x - 2.0 * x0) + (double)c3.y * ((double)c3.y - 2.0 * x1);
                s3b += (double)c3.z * ((double)c3.z - 2.0 * x2) + (double)c3.w * ((double)c3.w - 2.0 * x3);
            }
            double d0 = s0a + s0b, d1 = s1a + s1b, d2 = s2a + s2b, d3 = s3a + s3b;
            if (d0 < best || (d0 == best && k0        < bi)) { best = d0; bi = k0; }
            if (d1 < best || (d1 == best && k0 + 512  < bi)) { best = d1; bi = k0 + 512; }
            if (d2 < best || (d2 == best && k0 + 1024 < bi)) { best = d2; bi = k0 + 1024; }
            if (d3 < best || (d3 == best && k0 + 1536 < bi)) { best = d3; bi = k0 + 1536; }
        }
        rd[tid] = best; ri[tid] = bi;
        __syncthreads();
        for (int s = 256; s > 0; s >>= 1) {
            if (tid < s) {
                double od = rd[tid + s]; int oi = ri[tid + s];
                if (od < rd[tid] || (od == rd[tid] && oi < ri[tid])) { rd[tid] = od; ri[tid] = oi; }
            }
            __syncthreads();
        }
        if (tid == 0) bestIdx[n] = ri[0];
        __syncthreads();
    }
}

// ---------------------------------------------------------------- gather out rows
__global__ void gather_kernel(const float* __restrict__ cb, const int* __restrict__ bestIdx,
                              float* __restrict__ out)
{
    int t = blockIdx.x * 256 + threadIdx.x;
    int n = t >> 6, f4 = t & 63;
    int k = bestIdx[n];
    v4f v = *reinterpret_cast<const v4f*>(cb + (size_t)k * DIM + f4 * 4);
    ntstore4(out + (size_t)t * 4, v);
}

extern "C" void kernel_launch(void* const* d_in, const int* in_sizes, int n_in,
                              void* d_out, int out_size, void* d_ws, size_t ws_size,
                              hipStream_t stream)
{
    const float* x  = (const float*)d_in[0];
    const float* cb = (const float*)d_in[1];
    float* out = (float*)d_out;

    char* ws = (char*)d_ws;
    ushort_t* cbh      = (ushort_t*)ws;                     // 2 MB
    ushort_t* cbl      = (ushort_t*)(ws + 2097152);         // 2 MB
    float*    b2       = (float*)(ws + 4194304);            // 16 KB
    int*      bestIdx  = (int*)(ws + 4210688);              // 256 KB
    int*      cnts     = (int*)(ws + 4472832);              // 16 B  [cntFull, cnt2, cntLite, pad]
    int*      flagList = (int*)(ws + 4472848);              // 256 KB
    int*      flagList2= (int*)(ws + 4734992);              // 256 KB
    float*    ps1      = (float*)(ws + 4997136);            // 1 MB  [4][65536]
    float*    ps2      = (float*)(ws + 6045712);            // 1 MB
    int*      pidx     = (int*)(ws + 7094288);              // 1 MB  (end ~7.8 MB)
    int*      liteList = (int*)ps1;                         // reuse: consumed before refine1 writes ps1

    pack_cb       <<<dim3(512),  dim3(256), 0, stream>>>(cb, cbh, cbl, b2, cnts);
    argmin_kernel <<<dim3(N_TOK / BN), dim3(512), 0, stream>>>(x, cbh, b2, bestIdx, cnts, flagList, liteList);
    refine_lite   <<<dim3(512),  dim3(256), 0, stream>>>(x, cb, cnts, liteList, bestIdx);
    refine1_kernel<<<dim3(8192), dim3(512), 0, stream>>>(x, cbh, cbl, b2, cnts, flagList, ps1, ps2, pidx);
    merge_kernel  <<<dim3(64),   dim3(256), 0, stream>>>(cnts, flagList, ps1, ps2, pidx, bestIdx, flagList2);
    refine2_kernel<<<dim3(1024), dim3(512), 0, stream>>>(x, cb, cnts, flagList2, bestIdx);
    gather_kernel <<<dim3(N_TOK * 64 / 256), dim3(256), 0, stream>>>(cb, bestIdx, out);
}

// Round 19
// 215.888 us; speedup vs baseline: 1.5978x; 1.0276x over previous
//
#include <hip/hip_runtime.h>
#include <cstdint>

typedef _Float16 f16;
typedef __attribute__((ext_vector_type(8)))  f16   v8h;
typedef __attribute__((ext_vector_type(16))) float v16f;
typedef __attribute__((ext_vector_type(4)))  float v4f;
typedef unsigned short ushort_t;

#define N_TOK  65536
#define DIM    256
#define K_CB   4096
#define BN     128         // tokens per block (stage-0)
#define NCHUNK 128         // 8 kci x 16 d-chunks (wave slice = 64 codes)
#define MARGIN_S  3.0e-3f  // flag margin (~6 sigma incl. tag-packing perturbation)
#define MARGIN_S2 2.0e-4f  // stage-1 flag margin (~1000 sigma of 3-pass error)

#define MFMA(a,b,c) __builtin_amdgcn_mfma_f32_32x32x16_f16(a,b,c,0,0,0)
#define MED3(a,b,c) __builtin_amdgcn_fmed3f(a,b,c)

static __device__ __forceinline__ v4f ntload4(const void* p) {
    return __builtin_nontemporal_load((const v4f*)p);
}
static __device__ __forceinline__ void ntstore4(void* p, v4f v) {
    __builtin_nontemporal_store(v, (v4f*)p);
}

// decode a tag-packed score back to its global code index
static __device__ __forceinline__ int decode_k(float p, int wid, int lhalf) {
    unsigned tag = __float_as_uint(p) & 255u;
    int kci = tag >> 5, m = (tag >> 4) & 1, r = tag & 15;
    return (kci << 9) + wid * 64 + 4 * lhalf + (m << 5) + (r & 3) + 8 * (r >> 2);
}

// merge sorted triples (values desc) with indices for top-2
static __device__ __forceinline__ void merge5(float& s1, int& i1, float& s2, int& i2, float& s3,
                                              float o1, int oi1, float o2, int oi2, float o3) {
    bool aw = s1 >= o1;
    float w1 = aw ? s1 : o1;  int wi1 = aw ? i1 : oi1;
    float w2 = aw ? s2 : o2;  int wi2 = aw ? i2 : oi2;
    float w3 = aw ? s3 : o3;
    float l1 = aw ? o1 : s1;  int li1 = aw ? oi1 : i1;
    float l2 = aw ? o2 : s2;
    bool c = l1 > w2;
    s1 = w1; i1 = wi1;
    s2 = c ? l1 : w2; i2 = c ? li1 : wi2;
    s3 = c ? fmaxf(w2, l2) : fmaxf(w3, l1);
}

// ---------------------------------------------------------------- pack cb -> fp16 hi+lo panels, fused b2
// chunk g = kci*16 + ci (128 chunks, 16 KB each): [wave 8][khalf 2][code 64][8 d] f16
__global__ void pack_cb(const float* __restrict__ cb, ushort_t* __restrict__ cbh,
                        ushort_t* __restrict__ cbl, float* __restrict__ b2,
                        int* __restrict__ cnts) {
    __shared__ float red[256];
    int tid = threadIdx.x;
    if (blockIdx.x == 0 && tid < 4) cnts[tid] = 0;     // fused counter reset
    int gid = blockIdx.x * 256 + tid;                  // 0..131071
    int k = gid >> 5, grp = gid & 31;                  // grp = d/8
    int ci = grp >> 1, khalf = grp & 1;
    int kci = k >> 9, c = k & 511;
    int wav = c >> 6, cloc = c & 63;
    const float* src = cb + (size_t)k * DIM + grp * 8;
    float4 v0 = *(const float4*)(src);
    float4 v1 = *(const float4*)(src + 4);
    float f[8] = {v0.x, v0.y, v0.z, v0.w, v1.x, v1.y, v1.z, v1.w};
    v8h hv, lv;
    float ss = 0.f;
#pragma unroll
    for (int e = 0; e < 8; ++e) {
        f16 h = (f16)f[e];
        hv[e] = h;
        lv[e] = (f16)(f[e] - (float)h);
        ss = fmaf(f[e], f[e], ss);
    }
    size_t base = ((size_t)(kci * 16 + ci)) * 8192 + wav * 1024 + khalf * 512 + cloc * 8;
    *(v8h*)(cbh + base) = hv;
    *(v8h*)(cbl + base) = lv;
    red[tid] = ss;
    __syncthreads();
#pragma unroll
    for (int s = 16; s > 0; s >>= 1) {
        if ((tid & 31) < s) red[tid] += red[tid + s];
        __syncthreads();
    }
    if ((tid & 31) == 0) b2[gid >> 5] = red[tid];
}

// ---------------------------------------------------------------- stage-0: fp16 1-pass argmax(s), tag-packed top-3
__global__ __launch_bounds__(512, 2) void argmin_kernel(
    const float* __restrict__ x, const ushort_t* __restrict__ cbh,
    const float* __restrict__ b2, int* __restrict__ bestIdx,
    int* __restrict__ cnts, int* __restrict__ flagList, int* __restrict__ liteList)
{
    __shared__ __align__(16) f16   Xh[32 * 128 * 8];  // 64 KB: [dgrpIdx 32][token 128][8 d]
    __shared__ __align__(16) float B2s[K_CB];         // 16 KB

    const int tid   = threadIdx.x;
    const int wid   = tid >> 6;
    const int lane  = tid & 63;
    const int l31   = lane & 31;
    const int lhalf = lane >> 5;
    const int n0    = blockIdx.x * BN;

    // ---- stage x tile (hi only, NON-TEMPORAL: x has zero reuse, keep cbh L2-resident)
    {
        const int token = tid >> 2, dseg = tid & 3;   // each thread: 64 d of one token
        const float* xr = x + (size_t)(n0 + token) * DIM + dseg * 64;
#pragma unroll
        for (int sgrp = 0; sgrp < 8; ++sgrp) {
            v4f a = ntload4(xr + 8 * sgrp);
            v4f b = ntload4(xr + 8 * sgrp + 4);
            float f[8] = {a.x, a.y, a.z, a.w, b.x, b.y, b.z, b.w};
            v8h hv;
#pragma unroll
            for (int e = 0; e < 8; ++e) hv[e] = (f16)f[e];
            *(v8h*)(Xh + ((dseg * 8 + sgrp) * 128 + token) * 8) = hv;
        }
        const int o = tid * 8;
        *(float4*)(B2s + o)     = *(const float4*)(b2 + o);
        *(float4*)(B2s + o + 4) = *(const float4*)(b2 + o + 4);
    }
    __syncthreads();

    // per-lane A source: wave's 64-code slice; chunk stride 8192 ushorts (16 KB)
    const ushort_t* ap = cbh + (size_t)wid * 1024 + (size_t)lhalf * 512 + (size_t)l31 * 8;

#define LOAD_A(A, g_) do { \
        const ushort_t* p_ = ap + (size_t)(g_) * 8192; \
        A##0 = *(const v8h*)(p_); A##1 = *(const v8h*)(p_ + 256); } while (0)
#define READ_B(B, g_) do { \
        int boff_ = ((((g_) & 15) * 2 + lhalf) * 128 + l31) * 8; \
        B##0 = *(const v8h*)(Xh + boff_);       B##1 = *(const v8h*)(Xh + boff_ + 256); \
        B##2 = *(const v8h*)(Xh + boff_ + 512); B##3 = *(const v8h*)(Xh + boff_ + 768); } while (0)
#define MFMA8(A, B) do { \
        acc[0][0] = MFMA(A##0, B##0, acc[0][0]); \
        acc[0][1] = MFMA(A##0, B##1, acc[0][1]); \
        acc[0][2] = MFMA(A##0, B##2, acc[0][2]); \
        acc[0][3] = MFMA(A##0, B##3, acc[0][3]); \
        acc[1][0] = MFMA(A##1, B##0, acc[1][0]); \
        acc[1][1] = MFMA(A##1, B##1, acc[1][1]); \
        acc[1][2] = MFMA(A##1, B##2, acc[1][2]); \
        acc[1][3] = MFMA(A##1, B##3, acc[1][3]); } while (0)

    v16f vzero;
#pragma unroll
    for (int r = 0; r < 16; ++r) vzero[r] = 0.0f;
    v16f acc[2][4];
#pragma unroll
    for (int a = 0; a < 2; ++a)
#pragma unroll
        for (int b = 0; b < 4; ++b) acc[a][b] = vzero;

    float b1d[4], b2d[4], b3d[4];
#pragma unroll
    for (int j = 0; j < 4; ++j) {
        b1d[j] = -3.0e38f; b2d[j] = -3.0e38f; b3d[j] = -3.0e38f;
    }

    v8h Aa0, Aa1, Ab0, Ab1;
    v8h Ba0, Ba1, Ba2, Ba3, Bb0, Bb1, Bb2, Bb3;

    LOAD_A(Aa, 0); READ_B(Ba, 0);
    LOAD_A(Ab, 1); READ_B(Bb, 1);

#pragma unroll 1
    for (int g = 0; g < NCHUNK; g += 2) {
        MFMA8(Aa, Ba);
        { int gp = (g + 2 < NCHUNK) ? g + 2 : 0; LOAD_A(Aa, gp); READ_B(Ba, gp); }
        MFMA8(Ab, Bb);
        { int gp = (g + 3 < NCHUNK) ? g + 3 : 0; LOAD_A(Ab, gp); READ_B(Bb, gp); }

        if ((g & 15) == 14) {       // ---- fold kci into tag-packed top-3 (5 ops/score), reset acc
            const int kci = g >> 4;
            const int bbase = (kci << 9) + wid * 64 + 4 * lhalf;
            const unsigned tagk = (unsigned)(kci << 5);
#pragma unroll
            for (int m = 0; m < 2; ++m) {
                const float* bp = B2s + bbase + m * 32;
                float4 q0 = *(const float4*)(bp);
                float4 q1 = *(const float4*)(bp + 8);
                float4 q2 = *(const float4*)(bp + 16);
                float4 q3 = *(const float4*)(bp + 24);
                float bw[16] = {q0.x, q0.y, q0.z, q0.w, q1.x, q1.y, q1.z, q1.w,
                                q2.x, q2.y, q2.z, q2.w, q3.x, q3.y, q3.z, q3.w};
#pragma unroll
                for (int j = 0; j < 4; ++j) {
#pragma unroll
                    for (int r = 0; r < 16; ++r) {
                        float sv = fmaf(-0.5f, bw[r], acc[m][j][r]);
                        unsigned tag = tagk | (unsigned)((m << 4) | r);   // uniform -> SALU
                        float pk = __uint_as_float((__float_as_uint(sv) & 0xFFFFFF00u) | tag);
                        b3d[j] = MED3(pk, b2d[j], b3d[j]);   // uses OLD b2d
                        b2d[j] = MED3(pk, b1d[j], b2d[j]);   // uses OLD b1d
                        b1d[j] = fmaxf(b1d[j], pk);
                    }
                    acc[m][j] = vzero;
                }
            }
        }
    }

    // ---- decode packed -> explicit indices (per-lane lhalf!), then merge lane halves
    int b1i[4], b2i[4];
#pragma unroll
    for (int j = 0; j < 4; ++j) {
        b1i[j] = decode_k(b1d[j], wid, lhalf);
        b2i[j] = decode_k(b2d[j], wid, lhalf);
    }
#pragma unroll
    for (int j = 0; j < 4; ++j) {
        float o1 = __shfl_xor(b1d[j], 32);
        float o2 = __shfl_xor(b2d[j], 32);
        float o3 = __shfl_xor(b3d[j], 32);
        int  oi1 = __shfl_xor(b1i[j], 32);
        int  oi2 = __shfl_xor(b2i[j], 32);
        merge5(b1d[j], b1i[j], b2d[j], b2i[j], b3d[j], o1, oi1, o2, oi2, o3);
    }

    __syncthreads();
    float* f1  = (float*)Xh;         // [8 waves][128 tokens] (Xh dead now; 20 KB)
    float* f2  = f1 + 1024;
    float* f3  = f2 + 1024;
    int*   fi1 = (int*)(f3 + 1024);
    int*   fi2 = fi1 + 1024;
    if (lane < 32) {
#pragma unroll
        for (int j = 0; j < 4; ++j) {
            int idx = wid * 128 + j * 32 + l31;
            f1[idx] = b1d[j]; f2[idx] = b2d[j]; f3[idx] = b3d[j];
            fi1[idx] = b1i[j]; fi2[idx] = b2i[j];
        }
    }
    __syncthreads();
    if (tid < BN) {
        float s1 = -3.0e38f, s2 = -3.0e38f, s3 = -3.0e38f;
        int i1 = 0x7fffffff, i2 = 0x7fffffff;
#pragma unroll
        for (int w = 0; w < 8; ++w) {
            int idx = w * 128 + tid;
            merge5(s1, i1, s2, i2, s3, f1[idx], fi1[idx], f2[idx], fi2[idx], f3[idx]);
        }
        int n = n0 + tid;
        bestIdx[n] = i1;
        if (s1 - s2 < MARGIN_S) {
            if (s1 - s3 < MARGIN_S) {        // 3+ candidates -> full re-scan path
                int pos = atomicAdd(&cnts[0], 1);
                flagList[pos] = n;
            } else {                          // exactly 2 candidates -> lite fp64 duel
                int pos = atomicAdd(&cnts[2], 1);
                liteList[pos] = (n << 12) | i2;
            }
        }
    }
}

// ---------------------------------------------------------------- refine-lite: fp64 duel between i1 and i2
__global__ __launch_bounds__(256) void refine_lite(
    const float* __restrict__ x, const float* __restrict__ cb,
    const int* __restrict__ cnts, const int* __restrict__ liteList,
    int* __restrict__ bestIdx)
{
    const int tid = threadIdx.x;
    const int w = tid >> 6, lane = tid & 63, l31 = lane & 31;
    const int cnt3 = cnts[2];
    for (int t = blockIdx.x * 4 + w; t < cnt3; t += gridDim.x * 4) {
        const int ent = liteList[t];
        const int n = ent >> 12, i2 = ent & 4095;
        const int i1 = bestIdx[n];
        const int code = (lane < 32) ? i1 : i2;
        const float* cr = cb + (size_t)code * DIM + l31 * 8;
        const float* xr = x + (size_t)n * DIM + l31 * 8;
        double s = 0.0;
#pragma unroll
        for (int d = 0; d < 8; ++d) {
            double c = cr[d];
            s += c * (c - 2.0 * (double)xr[d]);
        }
#pragma unroll
        for (int off = 1; off < 32; off <<= 1) s += __shfl_xor(s, off, 64);
        double so = __shfl_xor(s, 32, 64);
        if (lane == 0) {
            bestIdx[n] = (so < s || (so == s && i2 < i1)) ? i2 : i1;
        }
    }
}

// ---------------------------------------------------------------- stage-1: fp16 3-pass, codebook-QUARTER split
__global__ __launch_bounds__(512) void refine1_kernel(
    const float* __restrict__ x, const ushort_t* __restrict__ cbh,
    const ushort_t* __restrict__ cbl, const float* __restrict__ b2,
    const int* __restrict__ cnts, const int* __restrict__ flagList,
    float* __restrict__ ps1, float* __restrict__ ps2, int* __restrict__ pidx)
{
    __shared__ __align__(16) f16   Xh[32 * 32 * 8];   // 16 KB
    __shared__ __align__(16) f16   Xl[32 * 32 * 8];   // 16 KB
    __shared__ __align__(16) float B2q[1024];         // 4 KB (this quarter's b2)

    const int tid   = threadIdx.x;
    const int wid   = tid >> 6;
    const int lane  = tid & 63;
    const int l31   = lane & 31;
    const int lhalf = lane >> 5;
    const int grpI  = blockIdx.x >> 2;
    const int qid   = blockIdx.x & 3;
    const int cnt   = cnts[0];
    const int f0    = grpI * 32;
    if (f0 >= cnt) return;

    {
        const int token = tid >> 4, dseg = tid & 15;  // 16 d per thread
        const int f = f0 + token;
        const int n = (f < cnt) ? flagList[f] : 0;    // deterministic padding (token 0)
        const float* xr = x + (size_t)n * DIM + dseg * 16;
#pragma unroll
        for (int s = 0; s < 2; ++s) {
            v4f a = ntload4(xr + 8 * s);
            v4f b = ntload4(xr + 8 * s + 4);
            float f8[8] = {a.x, a.y, a.z, a.w, b.x, b.y, b.z, b.w};
            v8h hv, lv;
#pragma unroll
            for (int e = 0; e < 8; ++e) {
                f16 h = (f16)f8[e];
                hv[e] = h; lv[e] = (f16)(f8[e] - (float)h);
            }
            int grp = dseg * 2 + s;                   // 0..31
            *(v8h*)(Xh + (grp * 32 + token) * 8) = hv;
            *(v8h*)(Xl + (grp * 32 + token) * 8) = lv;
        }
        if (tid < 256) *(float4*)(B2q + tid * 4) = *(const float4*)(b2 + qid * 1024 + tid * 4);
    }
    __syncthreads();

    const size_t qoff = (size_t)qid * 32 * 8192;
    const size_t loff = (size_t)wid * 1024 + (size_t)lhalf * 512 + (size_t)l31 * 8;
    const ushort_t* aph = cbh + qoff + loff;
    const ushort_t* apl = cbl + qoff + loff;

#define LOAD_A6(H0_, H1_, L0_, L1_, g_) do { \
        const ushort_t* ph_ = aph + (size_t)(g_) * 8192; \
        const ushort_t* pl_ = apl + (size_t)(g_) * 8192; \
        H0_ = *(const v8h*)(ph_); H1_ = *(const v8h*)(ph_ + 256); \
        L0_ = *(const v8h*)(pl_); L1_ = *(const v8h*)(pl_ + 256); } while (0)
#define READ_B6(BH_, BL_, g_) do { \
        int boff_ = ((((g_) & 15) * 2 + lhalf) * 32 + l31) * 8; \
        BH_ = *(const v8h*)(Xh + boff_); BL_ = *(const v8h*)(Xl + boff_); } while (0)
#define MFMA6(H0_, H1_, L0_, L1_, BH_, BL_) do { \
        acc0 = MFMA(H0_, BH_, acc0); acc1 = MFMA(H1_, BH_, acc1); \
        acc0 = MFMA(H0_, BL_, acc0); acc1 = MFMA(H1_, BL_, acc1); \
        acc0 = MFMA(L0_, BH_, acc0); acc1 = MFMA(L1_, BH_, acc1); } while (0)

    v16f vzero;
#pragma unroll
    for (int r = 0; r < 16; ++r) vzero[r] = 0.0f;
    v16f acc0 = vzero, acc1 = vzero;
    float b1d = -3.0e38f, b2d = -3.0e38f; int b1i = 0x7fffffff;

    v8h Ha0, Ha1, La0, La1, Hb0, Hb1, Lb0, Lb1;
    v8h BHa, BLa, BHb, BLb;

    LOAD_A6(Ha0, Ha1, La0, La1, 0); READ_B6(BHa, BLa, 0);
    LOAD_A6(Hb0, Hb1, Lb0, Lb1, 1); READ_B6(BHb, BLb, 1);

#pragma unroll 1
    for (int gl = 0; gl < 32; gl += 2) {
        MFMA6(Ha0, Ha1, La0, La1, BHa, BLa);
        { int gp = (gl + 2 < 32) ? gl + 2 : 0; LOAD_A6(Ha0, Ha1, La0, La1, gp); READ_B6(BHa, BLa, gp); }
        MFMA6(Hb0, Hb1, Lb0, Lb1, BHb, BLb);
        { int gp = (gl + 3 < 32) ? gl + 3 : 0; LOAD_A6(Hb0, Hb1, Lb0, Lb1, gp); READ_B6(BHb, BLb, gp); }

        if ((gl & 15) == 14) {
            const int kci_l = gl >> 4;
            const int bb_l  = (kci_l << 9) + wid * 64 + 4 * lhalf;
#pragma unroll
            for (int m = 0; m < 2; ++m) {
                const float* bp = B2q + bb_l + m * 32;
                float4 q0 = *(const float4*)(bp);
                float4 q1 = *(const float4*)(bp + 8);
                float4 q2 = *(const float4*)(bp + 16);
                float4 q3 = *(const float4*)(bp + 24);
                float bw[16] = {q0.x, q0.y, q0.z, q0.w, q1.x, q1.y, q1.z, q1.w,
                                q2.x, q2.y, q2.z, q2.w, q3.x, q3.y, q3.z, q3.w};
                const int kbase = qid * 1024 + bb_l + m * 32;
                v16f a = (m == 0) ? acc0 : acc1;
#pragma unroll
                for (int r = 0; r < 16; ++r) {
                    float sv = fmaf(-0.5f, bw[r], a[r]);
                    int k = kbase + (r & 3) + 8 * (r >> 2);
                    bool better = sv > b1d;
                    b2d = MED3(sv, b1d, b2d);
                    b1d = fmaxf(b1d, sv);
                    b1i = better ? k : b1i;
                }
            }
            acc0 = vzero; acc1 = vzero;
        }
    }

    {   // merge lane halves
        float o1 = __shfl_xor(b1d, 32);
        float o2 = __shfl_xor(b2d, 32);
        int   oi = __shfl_xor(b1i, 32);
        bool ow = o1 > b1d;
        float nb2 = fmaxf(fminf(b1d, o1), fmaxf(b2d, o2));
        b1i = ow ? oi : b1i;
        b1d = fmaxf(b1d, o1);
        b2d = nb2;
    }
    __syncthreads();
    float* f1 = (float*)Xh;          // [8 waves][32 tokens]
    float* f2 = f1 + 256;
    int*   fi = (int*)(f2 + 256);
    if (lane < 32) {
        int idx = wid * 32 + l31;
        f1[idx] = b1d; f2[idx] = b2d; fi[idx] = b1i;
    }
    __syncthreads();
    if (tid < 32 && f0 + tid < cnt) {
        float s1 = -3.0e38f, s2 = -3.0e38f; int si = 0x7fffffff;
#pragma unroll
        for (int w = 0; w < 8; ++w) {
            float c1 = f1[w * 32 + tid], c2 = f2[w * 32 + tid];
            int  ci1 = fi[w * 32 + tid];
            bool ow = c1 > s1;
            float nb2 = fmaxf(fminf(s1, c1), fmaxf(s2, c2));
            si = ow ? ci1 : si; s1 = fmaxf(s1, c1); s2 = nb2;
        }
        const int f = f0 + tid;
        ps1 [qid * 65536 + f] = s1;
        ps2 [qid * 65536 + f] = s2;
        pidx[qid * 65536 + f] = si;
    }
}

// ---------------------------------------------------------------- merge quarters -> bestIdx + flagList2
__global__ void merge_kernel(int* __restrict__ cnts, const int* __restrict__ flagList,
                             const float* __restrict__ ps1, const float* __restrict__ ps2,
                             const int* __restrict__ pidx, int* __restrict__ bestIdx,
                             int* __restrict__ flagList2)
{
    const int cnt = cnts[0];
    for (int f = blockIdx.x * 256 + threadIdx.x; f < cnt; f += gridDim.x * 256) {
        float s1 = -3.0e38f, s2 = -3.0e38f; int si = 0x7fffffff;
#pragma unroll
        for (int q = 0; q < 4; ++q) {
            float c1 = ps1[q * 65536 + f], c2 = ps2[q * 65536 + f];
            int  ci1 = pidx[q * 65536 + f];
            bool ow = c1 > s1;
            float nb2 = fmaxf(fminf(s1, c1), fmaxf(s2, c2));
            si = ow ? ci1 : si; s1 = fmaxf(s1, c1); s2 = nb2;
        }
        const int n = flagList[f];
        bestIdx[n] = si;
        if (s1 - s2 < MARGIN_S2) {           // still near a boundary -> fp64 exact
            int pos = atomicAdd(&cnts[1], 1);
            flagList2[pos] = n;
        }
    }
}

// ---------------------------------------------------------------- stage-2: fp64 exact full scan
__global__ __launch_bounds__(512) void refine2_kernel(
    const float* __restrict__ x, const float* __restrict__ cb,
    const int* __restrict__ cnts, const int* __restrict__ flagList2,
    int* __restrict__ bestIdx)
{
    __shared__ float  xr[DIM];
    __shared__ double rd[512];
    __shared__ int    ri[512];
    const int tid = threadIdx.x;
    const int cnt2 = cnts[1];
    for (int f = blockIdx.x; f < cnt2; f += gridDim.x) {
        const int n = flagList2[f];
        __syncthreads();
        if (tid < 64) {
            v4f v = ntload4(x + (size_t)n * DIM + tid * 4);
            xr[tid * 4 + 0] = v.x; xr[tid * 4 + 1] = v.y;
            xr[tid * 4 + 2] = v.z; xr[tid * 4 + 3] = v.w;
        }
        __syncthreads();
        double best = 1e300; int bi = 0x7fffffff;
#pragma unroll
        for (int grp = 0; grp < 2; ++grp) {
            const int k0 = grp * 2048 + tid;
            const float4* cr0 = reinterpret_cast<const float4*>(cb + (size_t)k0 * DIM);
            const float4* cr1 = reinterpret_cast<const float4*>(cb + (size_t)(k0 + 512) * DIM);
            const float4* cr2 = reinterpret_cast<const float4*>(cb + (size_t)(k0 + 1024) * DIM);
            const float4* cr3 = reinterpret_cast<const float4*>(cb + (size_t)(k0 + 1536) * DIM);
            double s0a = 0, s0b = 0, s1a = 0, s1b = 0;
            double s2a = 0, s2b = 0, s3a = 0, s3b = 0;
#pragma unroll 4
            for (int q = 0; q < 64; ++q) {
                float4 c0 = cr0[q], c1 = cr1[q], c2 = cr2[q], c3 = cr3[q];
                double x0 = xr[4 * q + 0], x1 = xr[4 * q + 1];
                double x2 = xr[4 * q + 2], x3 = xr[4 * q + 3];
                s0a += (double)c0.x * ((double)c0.x - 2.0 * x0) + (double)c0.y * ((double)c0.y - 2.0 * x1);
                s0b += (double)c0.z * ((double)c0.z - 2.0 * x2) + (double)c0.w * ((double)c0.w - 2.0 * x3);
                s1a += (double)c1.x * ((double)c1.x - 2.0 * x0) + (double)c1.y * ((double)c1.y - 2.0 * x1);
                s1b += (double)c1.z * ((double)c1.z - 2.0 * x2) + (double)c1.w * ((double)c1.w - 2.0 * x3);
                s2a += (double)c2.x * ((double)c2.x - 2.0 * x0) + (double)c2.y * ((double)c2.y - 2.0 * x1);
                s2b += (double)c2.z * ((double)c2.z - 2.0 * x2) + (double)c2.w * ((double)c2.w - 2.0 * x3);
                s3a += (double)c3.x * ((double)c3.x - 2.0 * x0) + (double)c3.y * ((double)c3.y - 2.0 * x1);
                s3b += (double)c3.z * ((double)c3.z - 2.0 * x2) + (double)c3.w * ((double)c3.w - 2.0 * x3);
            }
            double d0 = s0a + s0b, d1 = s1a + s1b, d2 = s2a + s2b, d3 = s3a + s3b;
            if (d0 < best || (d0 == best && k0        < bi)) { best = d0; bi = k0; }
            if (d1 < best || (d1 == best && k0 + 512  < bi)) { best = d1; bi = k0 + 512; }
            if (d2 < best || (d2 == best && k0 + 1024 < bi)) { best = d2; bi = k0 + 1024; }
            if (d3 < best || (d3 == best && k0 + 1536 < bi)) { best = d3; bi = k0 + 1536; }
        }
        rd[tid] = best; ri[tid] = bi;
        __syncthreads();
        for (int s = 256; s > 0; s >>= 1) {
            if (tid < s) {
                double od = rd[tid + s]; int oi = ri[tid + s];
                if (od < rd[tid] || (od == rd[tid] && oi < ri[tid])) { rd[tid] = od; ri[tid] = oi; }
            }
            __syncthreads();
        }
        if (tid == 0) bestIdx[n] = ri[0];
        __syncthreads();
    }
}

// ---------------------------------------------------------------- gather out rows
__global__ void gather_kernel(const float* __restrict__ cb, const int* __restrict__ bestIdx,
                              float* __restrict__ out)
{
    int t = blockIdx.x * 256 + threadIdx.x;
    int n = t >> 6, f4 = t & 63;
    int k = bestIdx[n];
    v4f v = *reinterpret_cast<const v4f*>(cb + (size_t)k * DIM + f4 * 4);
    ntstore4(out + (size_t)t * 4, v);
}

extern "C" void kernel_launch(void* const* d_in, const int* in_sizes, int n_in,
                              void* d_out, int out_size, void* d_ws, size_t ws_size,
                              hipStream_t stream)
{
    const float* x  = (const float*)d_in[0];
    const float* cb = (const float*)d_in[1];
    float* out = (float*)d_out;

    char* ws = (char*)d_ws;
    ushort_t* cbh      = (ushort_t*)ws;                     // 2 MB
    ushort_t* cbl      = (ushort_t*)(ws + 2097152);         // 2 MB
    float*    b2       = (float*)(ws + 4194304);            // 16 KB
    int*      bestIdx  = (int*)(ws + 4210688);              // 256 KB
    int*      cnts     = (int*)(ws + 4472832);              // 16 B  [cntFull, cnt2, cntLite, pad]
    int*      flagList = (int*)(ws + 4472848);              // 256 KB
    int*      flagList2= (int*)(ws + 4734992);              // 256 KB
    float*    ps1      = (float*)(ws + 4997136);            // 1 MB  [4][65536]
    float*    ps2      = (float*)(ws + 6045712);            // 1 MB
    int*      pidx     = (int*)(ws + 7094288);              // 1 MB  (end ~7.8 MB)
    int*      liteList = (int*)ps1;                         // reuse: consumed before refine1 writes ps1

    pack_cb       <<<dim3(512),  dim3(256), 0, stream>>>(cb, cbh, cbl, b2, cnts);
    argmin_kernel <<<dim3(N_TOK / BN), dim3(512), 0, stream>>>(x, cbh, b2, bestIdx, cnts, flagList, liteList);
    refine_lite   <<<dim3(512),  dim3(256), 0, stream>>>(x, cb, cnts, liteList, bestIdx);
    refine1_kernel<<<dim3(8192), dim3(512), 0, stream>>>(x, cbh, cbl, b2, cnts, flagList, ps1, ps2, pidx);
    merge_kernel  <<<dim3(64),   dim3(256), 0, stream>>>(cnts, flagList, ps1, ps2, pidx, bestIdx, flagList2);
    refine2_kernel<<<dim3(1024), dim3(512), 0, stream>>>(x, cb, cnts, flagList2, bestIdx);
    gather_kernel <<<dim3(N_TOK * 64 / 256), dim3(256), 0, stream>>>(cb, bestIdx, out);
}